// Round 1
// baseline (605.856 us; speedup 1.0000x reference)
//
#include <hip/hip_runtime.h>

typedef unsigned short u16;
typedef unsigned int u32;
typedef short short8 __attribute__((ext_vector_type(8)));
typedef u16 u16x8 __attribute__((ext_vector_type(8)));
typedef u16 u16x4 __attribute__((ext_vector_type(4)));
typedef float f32x4 __attribute__((ext_vector_type(4)));

__device__ __forceinline__ u16 f2bf(float f) {
  u32 u = __builtin_bit_cast(u32, f);
  u += 0x7fff + ((u >> 16) & 1);   // RNE
  return (u16)(u >> 16);
}

// ---------------- f32 -> bf16 convert (vectorized) ----------------
__global__ __launch_bounds__(256) void cvt_bf16(const float* __restrict__ src,
                                                u16* __restrict__ dst, int n4) {
  int i = blockIdx.x * 256 + threadIdx.x;
  if (i >= n4) return;
  float4 f = reinterpret_cast<const float4*>(src)[i];
  u16x4 o;
  o.x = f2bf(f.x); o.y = f2bf(f.y); o.z = f2bf(f.z); o.w = f2bf(f.w);
  reinterpret_cast<u16x4*>(dst)[i] = o;
}

// ---------------- GEMM: C[M][N] = A[M][K] * B[N][K]^T + bias ----------------
// A,B bf16 row-major; C -> bf16 (Cb) or f32 (Cf). 128x128 tile, BK=32,
// 256 threads = 4 waves in 2x2, each wave 64x64 = 4x4 mfma_16x16x32 frags.
#define BM 128
#define BN 128
#define BK 32
#define LDT 40   // padded LDS stride (bf16 elems): 80B -> 2-way conflicts only

__global__ __launch_bounds__(256) void gemm_bt(
    const u16* __restrict__ A, const u16* __restrict__ B,
    const float* __restrict__ bias,
    u16* __restrict__ Cb, float* __restrict__ Cf,
    int K, int ldc, int ccol0)
{
  __shared__ __align__(16) u16 As[BM * LDT];
  __shared__ __align__(16) u16 Bs[BN * LDT];
  const int t  = threadIdx.x;
  const int l  = t & 63;
  const int w  = t >> 6;
  const int lg = l >> 4;          // 0..3
  const int lr = l & 15;
  const int m0 = blockIdx.y * BM;
  const int n0 = blockIdx.x * BN;
  const int wr = (w >> 1) * 64;   // wave row origin in tile
  const int wc = (w & 1) * 64;    // wave col origin in tile
  const int sr = t >> 2;          // staging row 0..63
  const int sc = (t & 3) * 8;     // staging col 0,8,16,24
  const int ko = lg * 8;          // fragment k offset within BK

  f32x4 acc[4][4];
#pragma unroll
  for (int i = 0; i < 4; ++i)
#pragma unroll
    for (int j = 0; j < 4; ++j) acc[i][j] = (f32x4){0.f, 0.f, 0.f, 0.f};

  for (int k0 = 0; k0 < K; k0 += BK) {
    __syncthreads();
#pragma unroll
    for (int p = 0; p < 2; ++p) {
      int r = sr + 64 * p;
      short8 va = *reinterpret_cast<const short8*>(A + (size_t)(m0 + r) * K + k0 + sc);
      *reinterpret_cast<short8*>(&As[r * LDT + sc]) = va;
      short8 vb = *reinterpret_cast<const short8*>(B + (size_t)(n0 + r) * K + k0 + sc);
      *reinterpret_cast<short8*>(&Bs[r * LDT + sc]) = vb;
    }
    __syncthreads();
    short8 af[4], bf[4];
#pragma unroll
    for (int i = 0; i < 4; ++i)
      af[i] = *reinterpret_cast<const short8*>(&As[(wr + 16 * i + lr) * LDT + ko]);
#pragma unroll
    for (int j = 0; j < 4; ++j)
      bf[j] = *reinterpret_cast<const short8*>(&Bs[(wc + 16 * j + lr) * LDT + ko]);
#pragma unroll
    for (int i = 0; i < 4; ++i)
#pragma unroll
      for (int j = 0; j < 4; ++j)
        acc[i][j] = __builtin_amdgcn_mfma_f32_16x16x32_bf16(af[i], bf[j], acc[i][j], 0, 0, 0);
  }

  // epilogue: C layout col = lane&15, row = (lane>>4)*4 + r  [m89/m91]
#pragma unroll
  for (int i = 0; i < 4; ++i) {
#pragma unroll
    for (int j = 0; j < 4; ++j) {
      int col = n0 + wc + 16 * j + lr;
      float bv = bias[col];
#pragma unroll
      for (int r = 0; r < 4; ++r) {
        int row = m0 + wr + 16 * i + lg * 4 + r;
        float val = acc[i][j][r] + bv;
        if (Cb) Cb[(size_t)row * ldc + ccol0 + col] = f2bf(val);
        else    Cf[(size_t)row * ldc + col] = val;
      }
    }
  }
}

// ---------------- Flash attention (causal), per (b,h), 64 q-rows/block ------
// QKV: [8192][3072] bf16 (cols 0:1024 Q, 1024:2048 K, 2048:3072 V, per-head 64)
// O:   [8192][1024] bf16
__global__ __launch_bounds__(256) void attn_fwd(const u16* __restrict__ QKV,
                                                u16* __restrict__ O) {
  __shared__ __align__(16) u16 Kt[64 * 72];       // K tile [kv][d], pad->72
  __shared__ __align__(16) u16 Vt[64 * 72];       // V transposed [d][kv]
  __shared__ __align__(16) u16 Pl[4 * 16 * 72];   // per-wave P [16][72]

  const int t  = threadIdx.x;
  const int l  = t & 63;
  const int w  = t >> 6;
  const int lg = l >> 4, lr = l & 15;
  const int qb = blockIdx.x;        // 0..31 : q block of 64 rows
  const int bh = blockIdx.y;        // 0..63
  const int b  = bh >> 4, h = bh & 15;
  const size_t rowb = (size_t)b * 2048;
  const int qcol = h * 64;
  const int kcol = 1024 + h * 64;
  const int vcol = 2048 + h * 64;

  // Q fragments for this wave's 16 q rows (d=64 -> 2 k-steps)
  short8 qf[2];
  {
    size_t qrow = rowb + (size_t)qb * 64 + w * 16 + lr;
#pragma unroll
    for (int ks = 0; ks < 2; ++ks)
      qf[ks] = *reinterpret_cast<const short8*>(QKV + qrow * 3072 + qcol + ks * 32 + lg * 8);
  }

  f32x4 o_acc[4];
#pragma unroll
  for (int df = 0; df < 4; ++df) o_acc[df] = (f32x4){0.f, 0.f, 0.f, 0.f};
  float m_st[4], l_st[4];
#pragma unroll
  for (int r = 0; r < 4; ++r) { m_st[r] = -1e30f; l_st[r] = 0.f; }

  for (int kb = 0; kb <= qb; ++kb) {
    __syncthreads();
    // ---- stage K tile [64][64] ----
    {
      int r = t >> 3;              // 0..31
      int c = (t & 7) * 8;
#pragma unroll
      for (int p = 0; p < 2; ++p) {
        int rr = r + 32 * p;
        short8 kv8 = *reinterpret_cast<const short8*>(
            QKV + (rowb + (size_t)kb * 64 + rr) * 3072 + kcol + c);
        *reinterpret_cast<short8*>(&Kt[rr * 72 + c]) = kv8;
      }
      // ---- stage V transposed: Vt[d][kv] ----
      int r0 = (t >> 3) * 2;       // even 0..62
      const u16* vp = QKV + (rowb + (size_t)kb * 64 + r0) * 3072 + vcol + c;
      u16x8 v0 = *reinterpret_cast<const u16x8*>(vp);
      u16x8 v1 = *reinterpret_cast<const u16x8*>(vp + 3072);
#pragma unroll
      for (int j = 0; j < 8; ++j) {
        u32 pk = (u32)v0[j] | ((u32)v1[j] << 16);
        *reinterpret_cast<u32*>(&Vt[(c + j) * 72 + r0]) = pk;
      }
    }
    __syncthreads();

    // ---- S = Q K^T (this wave's 16 rows x 64 kv) ----
    f32x4 s[4];
#pragma unroll
    for (int nf = 0; nf < 4; ++nf) s[nf] = (f32x4){0.f, 0.f, 0.f, 0.f};
#pragma unroll
    for (int ks = 0; ks < 2; ++ks)
#pragma unroll
      for (int nf = 0; nf < 4; ++nf) {
        short8 kf = *reinterpret_cast<const short8*>(&Kt[(16 * nf + lr) * 72 + ks * 32 + lg * 8]);
        s[nf] = __builtin_amdgcn_mfma_f32_16x16x32_bf16(qf[ks], kf, s[nf], 0, 0, 0);
      }

    // ---- scale + causal mask (diag block only) ----
    const bool diag = (kb == qb);
#pragma unroll
    for (int nf = 0; nf < 4; ++nf)
#pragma unroll
      for (int r = 0; r < 4; ++r) {
        float x = s[nf][r] * 0.125f;
        if (diag) {
          int kg = 16 * nf + lr;
          int qg = w * 16 + lg * 4 + r;
          if (kg > qg) x = -1e30f;
        }
        s[nf][r] = x;
      }

    // ---- online softmax (rows live in 16-lane groups) ----
#pragma unroll
    for (int r = 0; r < 4; ++r) {
      float mx = fmaxf(fmaxf(s[0][r], s[1][r]), fmaxf(s[2][r], s[3][r]));
      mx = fmaxf(mx, __shfl_xor(mx, 1));
      mx = fmaxf(mx, __shfl_xor(mx, 2));
      mx = fmaxf(mx, __shfl_xor(mx, 4));
      mx = fmaxf(mx, __shfl_xor(mx, 8));
      float mnew = fmaxf(m_st[r], mx);
      float alpha = __expf(m_st[r] - mnew);
      m_st[r] = mnew;
      float ps = 0.f;
#pragma unroll
      for (int nf = 0; nf < 4; ++nf) {
        float p = __expf(s[nf][r] - mnew);
        s[nf][r] = p;
        ps += p;
      }
      ps += __shfl_xor(ps, 1);
      ps += __shfl_xor(ps, 2);
      ps += __shfl_xor(ps, 4);
      ps += __shfl_xor(ps, 8);
      l_st[r] = l_st[r] * alpha + ps;
#pragma unroll
      for (int df = 0; df < 4; ++df) o_acc[df][r] *= alpha;
    }

    // ---- P -> LDS (bf16), then PV via MFMA ----
#pragma unroll
    for (int nf = 0; nf < 4; ++nf)
#pragma unroll
      for (int r = 0; r < 4; ++r)
        Pl[(w * 16 + lg * 4 + r) * 72 + 16 * nf + lr] = f2bf(s[nf][r]);
    __syncthreads();
#pragma unroll
    for (int ks = 0; ks < 2; ++ks) {
      short8 pa = *reinterpret_cast<const short8*>(&Pl[(w * 16 + lr) * 72 + ks * 32 + lg * 8]);
#pragma unroll
      for (int df = 0; df < 4; ++df) {
        short8 vf = *reinterpret_cast<const short8*>(&Vt[(16 * df + lr) * 72 + ks * 32 + lg * 8]);
        o_acc[df] = __builtin_amdgcn_mfma_f32_16x16x32_bf16(pa, vf, o_acc[df], 0, 0, 0);
      }
    }
  }

  // ---- normalize + write ----
  size_t orow0 = rowb + (size_t)qb * 64 + w * 16;
#pragma unroll
  for (int df = 0; df < 4; ++df)
#pragma unroll
    for (int r = 0; r < 4; ++r) {
      float val = o_acc[df][r] / l_st[r];
      O[(orow0 + lg * 4 + r) * 1024 + h * 64 + 16 * df + lr] = f2bf(val);
    }
}

// ---------------- host launch ----------------
extern "C" void kernel_launch(void* const* d_in, const int* in_sizes, int n_in,
                              void* d_out, int out_size, void* d_ws, size_t ws_size,
                              hipStream_t stream) {
  const float* q  = (const float*)d_in[0];
  const float* k  = (const float*)d_in[1];
  const float* v  = (const float*)d_in[2];
  // d_in[3] = mask: known causal tril -> applied analytically, never read
  const float* wq = (const float*)d_in[4];
  const float* bq = (const float*)d_in[5];
  const float* wk = (const float*)d_in[6];
  const float* bk = (const float*)d_in[7];
  const float* wv = (const float*)d_in[8];
  const float* bv = (const float*)d_in[9];
  const float* wo = (const float*)d_in[10];
  const float* bo = (const float*)d_in[11];
  float* out = (float*)d_out;

  u16* ws = (u16*)d_ws;
  const size_t NE = 8192ull * 1024;       // 8,388,608 elems
  const size_t WE = 1024ull * 1024;
  u16* Xq   = ws;
  u16* Xk   = Xq + NE;
  u16* Xv   = Xk + NE;
  u16* Wq   = Xv + NE;
  u16* Wk   = Wq + WE;
  u16* Wv   = Wk + WE;
  u16* Wo   = Wv + WE;
  u16* QKVp = Wo + WE;                    // [8192][3072]
  u16* AO   = QKVp + 8192ull * 3072;      // [8192][1024]

  cvt_bf16<<<8192, 256, 0, stream>>>(q, Xq, (int)(NE / 4));
  cvt_bf16<<<8192, 256, 0, stream>>>(k, Xk, (int)(NE / 4));
  cvt_bf16<<<8192, 256, 0, stream>>>(v, Xv, (int)(NE / 4));
  cvt_bf16<<<1024, 256, 0, stream>>>(wq, Wq, (int)(WE / 4));
  cvt_bf16<<<1024, 256, 0, stream>>>(wk, Wk, (int)(WE / 4));
  cvt_bf16<<<1024, 256, 0, stream>>>(wv, Wv, (int)(WE / 4));
  cvt_bf16<<<1024, 256, 0, stream>>>(wo, Wo, (int)(WE / 4));

  dim3 gg(8, 64);  // N/128, M/128
  gemm_bt<<<gg, 256, 0, stream>>>(Xq, Wq, bq, QKVp, nullptr, 1024, 3072, 0);
  gemm_bt<<<gg, 256, 0, stream>>>(Xk, Wk, bk, QKVp, nullptr, 1024, 3072, 1024);
  gemm_bt<<<gg, 256, 0, stream>>>(Xv, Wv, bv, QKVp, nullptr, 1024, 3072, 2048);

  attn_fwd<<<dim3(32, 64), 256, 0, stream>>>(QKVp, AO);

  gemm_bt<<<gg, 256, 0, stream>>>(AO, Wo, bo, nullptr, out, 1024, 1024, 0);
}

// Round 2
// 465.612 us; speedup vs baseline: 1.3012x; 1.3012x over previous
//
#include <hip/hip_runtime.h>

typedef unsigned short u16;
typedef unsigned int u32;
typedef short short8 __attribute__((ext_vector_type(8)));
typedef u16 u16x8 __attribute__((ext_vector_type(8)));
typedef u16 u16x4 __attribute__((ext_vector_type(4)));
typedef float f32x4 __attribute__((ext_vector_type(4)));
typedef float f32x16 __attribute__((ext_vector_type(16)));

__device__ __forceinline__ u16 f2bf(float f) {
  u32 u = __builtin_bit_cast(u32, f);
  u += 0x7fff + ((u >> 16) & 1);   // RNE
  return (u16)(u >> 16);
}

// async global->LDS 16B (m97 idiom). LDS dest must be wave-uniform-base + lane*16.
__device__ __forceinline__ void gload16(const u16* g, u16* l) {
  __builtin_amdgcn_global_load_lds(
      (const __attribute__((address_space(1))) u32*)(unsigned long long)(const void*)g,
      (__attribute__((address_space(3))) u32*)(u32)(unsigned long long)(void*)l,
      16, 0, 0);
}

// ---------------- fused f32 -> bf16 converts ----------------
__global__ __launch_bounds__(256) void cvt3(const float* __restrict__ a, const float* __restrict__ b,
                                            const float* __restrict__ c, u16* __restrict__ oa,
                                            u16* __restrict__ ob, u16* __restrict__ oc, int n4) {
  const int z = blockIdx.y;
  const float* s = z == 0 ? a : (z == 1 ? b : c);
  u16* d = z == 0 ? oa : (z == 1 ? ob : oc);
  int i = blockIdx.x * 256 + threadIdx.x;
  if (i >= n4) return;
  float4 f = reinterpret_cast<const float4*>(s)[i];
  u16x4 o;
  o.x = f2bf(f.x); o.y = f2bf(f.y); o.z = f2bf(f.z); o.w = f2bf(f.w);
  reinterpret_cast<u16x4*>(d)[i] = o;
}

__global__ __launch_bounds__(256) void cvt4(const float* __restrict__ a, const float* __restrict__ b,
                                            const float* __restrict__ c, const float* __restrict__ d0,
                                            u16* __restrict__ oa, u16* __restrict__ ob,
                                            u16* __restrict__ oc, u16* __restrict__ od, int n4) {
  const int z = blockIdx.y;
  const float* s = z == 0 ? a : (z == 1 ? b : (z == 2 ? c : d0));
  u16* d = z == 0 ? oa : (z == 1 ? ob : (z == 2 ? oc : od));
  int i = blockIdx.x * 256 + threadIdx.x;
  if (i >= n4) return;
  float4 f = reinterpret_cast<const float4*>(s)[i];
  u16x4 o;
  o.x = f2bf(f.x); o.y = f2bf(f.y); o.z = f2bf(f.z); o.w = f2bf(f.w);
  reinterpret_cast<u16x4*>(d)[i] = o;
}

// ---------------- GEMM core: C[M][N] = A[M][K] * B[N][K]^T + bias ----------------
// 128x128 tile, BK=32, global_load_lds staging with 2-bit XOR chunk swizzle
// applied on the GLOBAL source (LDS stays linear; frag reads apply same XOR).
__device__ __forceinline__ void gemm_core(const u16* __restrict__ A, const u16* __restrict__ Bm,
                                          const float* __restrict__ bias, u16* __restrict__ Cb,
                                          float* __restrict__ Cf, int K, int ldc, int ccol0) {
  __shared__ __align__(16) u16 As[128 * 32];
  __shared__ __align__(16) u16 Bs[128 * 32];
  const int t = threadIdx.x, l = t & 63, w = t >> 6;
  const int lg = l >> 4, lr = l & 15;
  const int m0 = blockIdx.y * 128, n0 = blockIdx.x * 128;
  const int wr = (w >> 1) * 64, wc = (w & 1) * 64;
  const int srow = w * 32 + (l >> 2);
  const int scol = ((l & 3) ^ ((l >> 2) & 3)) * 8;   // pre-swizzled source chunk
  const u16* ga = A + (size_t)(m0 + srow) * K + scol;
  const u16* gb = Bm + (size_t)(n0 + srow) * K + scol;
  u16* la = As + w * 1024 + l * 8;                   // linear dest = base + lane*16B
  u16* lb = Bs + w * 1024 + l * 8;
  const int ko = (lg ^ (lr & 3)) * 8;                // swizzled frag chunk

  f32x4 acc[4][4];
#pragma unroll
  for (int i = 0; i < 4; ++i)
#pragma unroll
    for (int j = 0; j < 4; ++j) acc[i][j] = (f32x4){0.f, 0.f, 0.f, 0.f};

  for (int k0 = 0; k0 < K; k0 += 32) {
    __syncthreads();
    gload16(ga + k0, la);
    gload16(ga + k0 + 16 * (size_t)K, la + 512);
    gload16(gb + k0, lb);
    gload16(gb + k0 + 16 * (size_t)K, lb + 512);
    __syncthreads();   // compiler drains vmcnt before barrier
    short8 af[4], bf[4];
#pragma unroll
    for (int i = 0; i < 4; ++i)
      af[i] = *reinterpret_cast<const short8*>(&As[(wr + 16 * i + lr) * 32 + ko]);
#pragma unroll
    for (int j = 0; j < 4; ++j)
      bf[j] = *reinterpret_cast<const short8*>(&Bs[(wc + 16 * j + lr) * 32 + ko]);
#pragma unroll
    for (int i = 0; i < 4; ++i)
#pragma unroll
      for (int j = 0; j < 4; ++j)
        acc[i][j] = __builtin_amdgcn_mfma_f32_16x16x32_bf16(af[i], bf[j], acc[i][j], 0, 0, 0);
  }

  // C layout (16x16x32): col=lane&15, row=(lane>>4)*4+r  [m89/m91]
#pragma unroll
  for (int i = 0; i < 4; ++i) {
#pragma unroll
    for (int j = 0; j < 4; ++j) {
      int col = n0 + wc + 16 * j + lr;
      float bv = bias[col];
#pragma unroll
      for (int r = 0; r < 4; ++r) {
        int row = m0 + wr + 16 * i + lg * 4 + r;
        float val = acc[i][j][r] + bv;
        if (Cb) Cb[(size_t)row * ldc + ccol0 + col] = f2bf(val);
        else    Cf[(size_t)row * ldc + col] = val;
      }
    }
  }
}

__global__ __launch_bounds__(256) void gemm_qkv(const u16* __restrict__ Xq, const u16* __restrict__ Xk,
                                                const u16* __restrict__ Xv, const u16* __restrict__ Wq,
                                                const u16* __restrict__ Wk, const u16* __restrict__ Wv,
                                                const float* __restrict__ bq, const float* __restrict__ bk,
                                                const float* __restrict__ bv, u16* __restrict__ QKV) {
  const int z = blockIdx.z;
  const u16* A = z == 0 ? Xq : (z == 1 ? Xk : Xv);
  const u16* B = z == 0 ? Wq : (z == 1 ? Wk : Wv);
  const float* bias = z == 0 ? bq : (z == 1 ? bk : bv);
  gemm_core(A, B, bias, QKV, nullptr, 1024, 3072, z * 1024);
}

__global__ __launch_bounds__(256) void gemm_out(const u16* __restrict__ AO, const u16* __restrict__ Wo,
                                                const float* __restrict__ bo, float* __restrict__ out) {
  gemm_core(AO, Wo, bo, nullptr, out, 1024, 1024, 0);
}

// ---------------- Flash attention (causal), swapped-QK^T, 32x32 MFMA ----------------
// 4 waves x 32 q-rows = 128 q/block. KV tile 64. QKV [8192][3072] bf16; O [8192][1024] bf16.
// S^T = mfma(A=K, B=Q): lane owns q-column (l&31); kv rows = (r&3)+8*(r>>2)+4*(l>>5).
// PV computes O^T = mfma(A=V^T, B=P): rescale stays per-lane scalar.
#define LDK 72

__global__ __launch_bounds__(256) void attn_fwd(const u16* __restrict__ QKV, u16* __restrict__ O) {
  __shared__ __align__(16) u16 Kt[64 * LDK];
  __shared__ __align__(16) u16 Vt[64 * LDK];   // transposed [d][kv]

  const int t = threadIdx.x;
  const int l = t & 63;
  const int w = t >> 6;
  const int lq = l & 31;
  const int hi = l >> 5;
  const int qblk = blockIdx.x;        // 0..15
  const int bh = blockIdx.y;          // 0..63
  const int b = bh >> 4, h = bh & 15;
  const size_t rowb = (size_t)b * 2048;
  const int qcol = h * 64, kcol = 1024 + h * 64, vcol = 2048 + h * 64;
  const int q0w = qblk * 128 + w * 32;
  const int qg = q0w + lq;            // this lane's q row (within sequence)
  const int nt = 2 * qblk + 2;        // KV-64 tiles for this block

  // Q fragments: B operand, lane holds col q=l&31, k = hi*8+j per K=16 step
  short8 qf[4];
  {
    const u16* qp = QKV + (rowb + qg) * 3072 + qcol + hi * 8;
#pragma unroll
    for (int ks = 0; ks < 4; ++ks)
      qf[ks] = *reinterpret_cast<const short8*>(qp + ks * 16);
  }

  f32x16 oa[2];
#pragma unroll
  for (int dt = 0; dt < 2; ++dt)
#pragma unroll
    for (int r = 0; r < 16; ++r) oa[dt][r] = 0.f;
  float m_run = -1e30f, l_run = 0.f;

  // staging maps (bank-clean): K rows by t&31, cols by t>>5; V same for transpose
  const int kr = t & 31, kc = (t >> 5) * 8;
  short8 ka0, ka1;
  u16x8 va0, va1;

  // prologue: tile 0
  {
    const u16* kp = QKV + (rowb + kr) * 3072 + kcol + kc;
    ka0 = *reinterpret_cast<const short8*>(kp);
    ka1 = *reinterpret_cast<const short8*>(kp + 32 * 3072);
    const u16* vp = QKV + (rowb + kr * 2) * 3072 + vcol + kc;
    va0 = *reinterpret_cast<const u16x8*>(vp);
    va1 = *reinterpret_cast<const u16x8*>(vp + 3072);
    *reinterpret_cast<short8*>(&Kt[kr * LDK + kc]) = ka0;
    *reinterpret_cast<short8*>(&Kt[(kr + 32) * LDK + kc]) = ka1;
#pragma unroll
    for (int j = 0; j < 8; ++j) {
      u32 pk = (u32)va0[j] | ((u32)va1[j] << 16);
      *reinterpret_cast<u32*>(&Vt[(kc + j) * LDK + kr * 2]) = pk;
    }
  }
  __syncthreads();

  for (int kb = 0; kb < nt; ++kb) {
    // T14: issue next tile's global loads before compute
    if (kb + 1 < nt) {
      const u16* kp = QKV + (rowb + (size_t)(kb + 1) * 64 + kr) * 3072 + kcol + kc;
      ka0 = *reinterpret_cast<const short8*>(kp);
      ka1 = *reinterpret_cast<const short8*>(kp + 32 * 3072);
      const u16* vp = QKV + (rowb + (size_t)(kb + 1) * 64 + kr * 2) * 3072 + vcol + kc;
      va0 = *reinterpret_cast<const u16x8*>(vp);
      va1 = *reinterpret_cast<const u16x8*>(vp + 3072);
    }

#pragma unroll
    for (int kt = 0; kt < 2; ++kt) {
      const int kv0 = kb * 64 + kt * 32;
      if (kv0 <= q0w) {            // wave-uniform causal guard (32-aligned both sides)
        // ---- S^T = K Q^T ----
        f32x16 s;
#pragma unroll
        for (int r = 0; r < 16; ++r) s[r] = 0.f;
#pragma unroll
        for (int ks = 0; ks < 4; ++ks) {
          short8 kf = *reinterpret_cast<const short8*>(&Kt[(kt * 32 + lq) * LDK + ks * 16 + hi * 8]);
          s = __builtin_amdgcn_mfma_f32_32x32x16_bf16(kf, qf[ks], s, 0, 0, 0);
        }
        // ---- scale + causal mask (diagonal subtile only) ----
        const bool diag = (kv0 == q0w);
        float p[16];
#pragma unroll
        for (int r = 0; r < 16; ++r) {
          float x = s[r] * 0.125f;
          if (diag) {
            int off = (r & 3) + 8 * (r >> 2) + 4 * hi;   // kv - kv0
            if (off > lq) x = -1e30f;
          }
          p[r] = x;
        }
        // ---- online softmax (per-lane q-column) ----
        float pm = p[0];
#pragma unroll
        for (int r = 1; r < 16; ++r) pm = fmaxf(pm, p[r]);
        pm = fmaxf(pm, __shfl_xor(pm, 32));
        float mnew = fmaxf(m_run, pm);
        bool grow = mnew > m_run;
        float alpha = __expf(m_run - mnew);
        m_run = mnew;
        float psum = 0.f;
#pragma unroll
        for (int r = 0; r < 16; ++r) {
          float e = __expf(p[r] - mnew);
          p[r] = e;
          psum += e;
        }
        psum += __shfl_xor(psum, 32);
        l_run = l_run * alpha + psum;
        if (__any(grow)) {        // T13 defer: skip O-rescale when max unchanged
#pragma unroll
          for (int dt = 0; dt < 2; ++dt)
#pragma unroll
            for (int r = 0; r < 16; ++r) oa[dt][r] *= alpha;
        }
        // ---- pack P -> bf16 + lane-pair exchange (T12 via shfl_xor 32) ----
        u32 P[8], X[8];
#pragma unroll
        for (int m2 = 0; m2 < 8; ++m2) {
          P[m2] = (u32)f2bf(p[2 * m2]) | ((u32)f2bf(p[2 * m2 + 1]) << 16);
          X[m2] = (u32)__shfl_xor((int)P[m2], 32);
        }
        short8 pf[2];
#pragma unroll
        for (int ks2 = 0; ks2 < 2; ++ks2) {
          union { u32 u[4]; short8 v; } uu;
          uu.u[0] = hi ? X[4 * ks2 + 2] : P[4 * ks2 + 0];
          uu.u[1] = hi ? X[4 * ks2 + 3] : P[4 * ks2 + 1];
          uu.u[2] = hi ? P[4 * ks2 + 2] : X[4 * ks2 + 0];
          uu.u[3] = hi ? P[4 * ks2 + 3] : X[4 * ks2 + 1];
          pf[ks2] = uu.v;
        }
        // ---- O^T += V^T P ----
#pragma unroll
        for (int ks2 = 0; ks2 < 2; ++ks2)
#pragma unroll
          for (int dt = 0; dt < 2; ++dt) {
            short8 vf = *reinterpret_cast<const short8*>(
                &Vt[(dt * 32 + lq) * LDK + kt * 32 + ks2 * 16 + hi * 8]);
            oa[dt] = __builtin_amdgcn_mfma_f32_32x32x16_bf16(vf, pf[ks2], oa[dt], 0, 0, 0);
          }
      }
    }
    __syncthreads();
    if (kb + 1 < nt) {
      *reinterpret_cast<short8*>(&Kt[kr * LDK + kc]) = ka0;
      *reinterpret_cast<short8*>(&Kt[(kr + 32) * LDK + kc]) = ka1;
#pragma unroll
      for (int j = 0; j < 8; ++j) {
        u32 pk = (u32)va0[j] | ((u32)va1[j] << 16);
        *reinterpret_cast<u32*>(&Vt[(kc + j) * LDK + kr * 2]) = pk;
      }
    }
    __syncthreads();
  }

  // ---- epilogue: normalize, lane-pair exchange to d-contiguous chunks, 16B stores ----
  const float inv = __builtin_amdgcn_rcpf(l_run);
  const size_t obase = (rowb + qg) * 1024 + h * 64;
#pragma unroll
  for (int dt = 0; dt < 2; ++dt) {
    u32 Bp[8], Xb[8];
#pragma unroll
    for (int m2 = 0; m2 < 8; ++m2) {
      Bp[m2] = (u32)f2bf(oa[dt][2 * m2] * inv) | ((u32)f2bf(oa[dt][2 * m2 + 1] * inv) << 16);
      Xb[m2] = (u32)__shfl_xor((int)Bp[m2], 32);
    }
    if (hi == dt) {
#pragma unroll
      for (int c = 0; c < 4; ++c) {
        union { u32 u[4]; short8 v; } uu;
        uu.u[0] = hi ? Xb[2 * c]     : Bp[2 * c];
        uu.u[1] = hi ? Xb[2 * c + 1] : Bp[2 * c + 1];
        uu.u[2] = hi ? Bp[2 * c]     : Xb[2 * c];
        uu.u[3] = hi ? Bp[2 * c + 1] : Xb[2 * c + 1];
        *reinterpret_cast<short8*>(&O[obase + dt * 32 + c * 8]) = uu.v;
      }
    }
  }
}

// ---------------- host launch ----------------
extern "C" void kernel_launch(void* const* d_in, const int* in_sizes, int n_in,
                              void* d_out, int out_size, void* d_ws, size_t ws_size,
                              hipStream_t stream) {
  const float* q  = (const float*)d_in[0];
  const float* k  = (const float*)d_in[1];
  const float* v  = (const float*)d_in[2];
  // d_in[3] = mask: known causal tril -> applied analytically
  const float* wq = (const float*)d_in[4];
  const float* bq = (const float*)d_in[5];
  const float* wk = (const float*)d_in[6];
  const float* bk = (const float*)d_in[7];
  const float* wv = (const float*)d_in[8];
  const float* bv = (const float*)d_in[9];
  const float* wo = (const float*)d_in[10];
  const float* bo = (const float*)d_in[11];
  float* out = (float*)d_out;

  u16* ws = (u16*)d_ws;
  const size_t NE = 8192ull * 1024;
  const size_t WE = 1024ull * 1024;
  u16* Xq   = ws;
  u16* Xk   = Xq + NE;
  u16* Xv   = Xk + NE;
  u16* Wq   = Xv + NE;
  u16* Wk   = Wq + WE;
  u16* Wv   = Wk + WE;
  u16* Wo   = Wv + WE;
  u16* QKVp = Wo + WE;                  // [8192][3072]
  u16* AO   = QKVp + 8192ull * 3072;    // [8192][1024]

  cvt3<<<dim3(8192, 3), 256, 0, stream>>>(q, k, v, Xq, Xk, Xv, (int)(NE / 4));
  cvt4<<<dim3(1024, 4), 256, 0, stream>>>(wq, wk, wv, wo, Wq, Wk, Wv, Wo, (int)(WE / 4));

  gemm_qkv<<<dim3(8, 64, 3), 256, 0, stream>>>(Xq, Xk, Xv, Wq, Wk, Wv, bq, bk, bv, QKVp);

  attn_fwd<<<dim3(16, 64), 256, 0, stream>>>(QKVp, AO);

  gemm_out<<<dim3(8, 64), 256, 0, stream>>>(AO, Wo, bo, out);
}

// Round 3
// 461.418 us; speedup vs baseline: 1.3130x; 1.0091x over previous
//
#include <hip/hip_runtime.h>

typedef unsigned short u16;
typedef unsigned int u32;
typedef short short8 __attribute__((ext_vector_type(8)));
typedef u16 u16x8 __attribute__((ext_vector_type(8)));
typedef u16 u16x4 __attribute__((ext_vector_type(4)));
typedef float f32x4 __attribute__((ext_vector_type(4)));
typedef float f32x16 __attribute__((ext_vector_type(16)));

__device__ __forceinline__ u16 f2bf(float f) {
  u32 u = __builtin_bit_cast(u32, f);
  u += 0x7fff + ((u >> 16) & 1);   // RNE
  return (u16)(u >> 16);
}
__device__ __forceinline__ float ex2(float x) {      // 2^x, single v_exp_f32
  float r; asm("v_exp_f32 %0, %1" : "=v"(r) : "v"(x)); return r;
}
__device__ __forceinline__ u32 cvtpk(float lo, float hi) {   // packed bf16
  u32 r; asm("v_cvt_pk_bf16_f32 %0, %1, %2" : "=v"(r) : "v"(lo), "v"(hi)); return r;
}

// async global->LDS 16B (m97 idiom). LDS dest = wave-uniform base + lane*16.
__device__ __forceinline__ void gload16(const u16* g, u16* l) {
  __builtin_amdgcn_global_load_lds(
      (const __attribute__((address_space(1))) u32*)(unsigned long long)(const void*)g,
      (__attribute__((address_space(3))) u32*)(u32)(unsigned long long)(void*)l,
      16, 0, 0);
}

// ---------------- fused f32 -> bf16 converts ----------------
__global__ __launch_bounds__(256) void cvt3(const float* __restrict__ a, const float* __restrict__ b,
                                            const float* __restrict__ c, u16* __restrict__ oa,
                                            u16* __restrict__ ob, u16* __restrict__ oc, int n4) {
  const int z = blockIdx.y;
  const float* s = z == 0 ? a : (z == 1 ? b : c);
  u16* d = z == 0 ? oa : (z == 1 ? ob : oc);
  int i = blockIdx.x * 256 + threadIdx.x;
  if (i >= n4) return;
  float4 f = reinterpret_cast<const float4*>(s)[i];
  u16x4 o;
  o.x = f2bf(f.x); o.y = f2bf(f.y); o.z = f2bf(f.z); o.w = f2bf(f.w);
  reinterpret_cast<u16x4*>(d)[i] = o;
}

__global__ __launch_bounds__(256) void cvt4(const float* __restrict__ a, const float* __restrict__ b,
                                            const float* __restrict__ c, const float* __restrict__ d0,
                                            u16* __restrict__ oa, u16* __restrict__ ob,
                                            u16* __restrict__ oc, u16* __restrict__ od, int n4) {
  const int z = blockIdx.y;
  const float* s = z == 0 ? a : (z == 1 ? b : (z == 2 ? c : d0));
  u16* d = z == 0 ? oa : (z == 1 ? ob : (z == 2 ? oc : od));
  int i = blockIdx.x * 256 + threadIdx.x;
  if (i >= n4) return;
  float4 f = reinterpret_cast<const float4*>(s)[i];
  u16x4 o;
  o.x = f2bf(f.x); o.y = f2bf(f.y); o.z = f2bf(f.z); o.w = f2bf(f.w);
  reinterpret_cast<u16x4*>(d)[i] = o;
}

// ---------------- GEMM: C = A * B^T + bias, scaled. 128x128 tile, BK=64 ----------------
__device__ __forceinline__ void gemm_core(const u16* __restrict__ A, const u16* __restrict__ Bm,
                                          const float* __restrict__ bias, u16* __restrict__ Cb,
                                          float* __restrict__ Cf, int K, int ldc, int ccol0,
                                          float cs) {
  __shared__ __align__(16) u16 As[2][128 * 32];
  __shared__ __align__(16) u16 Bs[2][128 * 32];
  const int t = threadIdx.x, l = t & 63, w = t >> 6;
  const int lg = l >> 4, lr = l & 15;
  const int m0 = blockIdx.y * 128, n0 = blockIdx.x * 128;
  const int wr = (w >> 1) * 64, wc = (w & 1) * 64;
  const int srow = w * 32 + (l >> 2);
  const int scol = ((l & 3) ^ ((l >> 2) & 3)) * 8;   // pre-swizzled source chunk
  const u16* ga = A + (size_t)(m0 + srow) * K + scol;
  const u16* gb = Bm + (size_t)(n0 + srow) * K + scol;
  const int ldst = w * 1024 + l * 8;                 // linear dest
  const int ko = (lg ^ (lr & 3)) * 8;                // swizzled frag chunk

  f32x4 acc[4][4];
#pragma unroll
  for (int i = 0; i < 4; ++i)
#pragma unroll
    for (int jj = 0; jj < 4; ++jj) acc[i][jj] = (f32x4){0.f, 0.f, 0.f, 0.f};

  for (int k0 = 0; k0 < K; k0 += 64) {
    __syncthreads();
#pragma unroll
    for (int hh = 0; hh < 2; ++hh) {
      gload16(ga + k0 + 32 * hh, &As[hh][ldst]);
      gload16(ga + k0 + 32 * hh + 16 * (size_t)K, &As[hh][ldst + 512]);
      gload16(gb + k0 + 32 * hh, &Bs[hh][ldst]);
      gload16(gb + k0 + 32 * hh + 16 * (size_t)K, &Bs[hh][ldst + 512]);
    }
    __syncthreads();   // drains vmcnt
#pragma unroll
    for (int hh = 0; hh < 2; ++hh) {
      short8 af[4], bf[4];
#pragma unroll
      for (int i = 0; i < 4; ++i)
        af[i] = *reinterpret_cast<const short8*>(&As[hh][(wr + 16 * i + lr) * 32 + ko]);
#pragma unroll
      for (int jj = 0; jj < 4; ++jj)
        bf[jj] = *reinterpret_cast<const short8*>(&Bs[hh][(wc + 16 * jj + lr) * 32 + ko]);
#pragma unroll
      for (int i = 0; i < 4; ++i)
#pragma unroll
        for (int jj = 0; jj < 4; ++jj)
          acc[i][jj] = __builtin_amdgcn_mfma_f32_16x16x32_bf16(af[i], bf[jj], acc[i][jj], 0, 0, 0);
    }
  }

  // C layout (16x16x32): col=lane&15, row=(lane>>4)*4+r  [m89/m91]
#pragma unroll
  for (int i = 0; i < 4; ++i) {
#pragma unroll
    for (int jj = 0; jj < 4; ++jj) {
      int col = n0 + wc + 16 * jj + lr;
      float bv = bias[col];
#pragma unroll
      for (int r = 0; r < 4; ++r) {
        int row = m0 + wr + 16 * i + lg * 4 + r;
        float val = (acc[i][jj][r] + bv) * cs;
        if (Cb) Cb[(size_t)row * ldc + ccol0 + col] = f2bf(val);
        else    Cf[(size_t)row * ldc + col] = val;
      }
    }
  }
}

// Q output is pre-scaled by log2(e)/8 so attention softmax runs in exp2 domain.
#define QSCALE 0.18033688011112042f

__global__ __launch_bounds__(256) void gemm_qkv(const u16* __restrict__ Xq, const u16* __restrict__ Xk,
                                                const u16* __restrict__ Xv, const u16* __restrict__ Wq,
                                                const u16* __restrict__ Wk, const u16* __restrict__ Wv,
                                                const float* __restrict__ bq, const float* __restrict__ bk,
                                                const float* __restrict__ bv, u16* __restrict__ QKV) {
  const int z = blockIdx.z;
  const u16* A = z == 0 ? Xq : (z == 1 ? Xk : Xv);
  const u16* B = z == 0 ? Wq : (z == 1 ? Wk : Wv);
  const float* bias = z == 0 ? bq : (z == 1 ? bk : bv);
  gemm_core(A, B, bias, QKV, nullptr, 1024, 3072, z * 1024, z == 0 ? QSCALE : 1.0f);
}

__global__ __launch_bounds__(256) void gemm_out(const u16* __restrict__ AO, const u16* __restrict__ Wo,
                                                const float* __restrict__ bo, float* __restrict__ out) {
  gemm_core(AO, Wo, bo, nullptr, out, 1024, 1024, 0, 1.0f);
}

// ---------------- Flash attention (causal), balanced-pair, 32x32 MFMA ----------------
// Block j (j=0..15) owns q-tiles j and 31-j (64 rows each, 2 waves x 32 rows),
// one shared KV loop over tiles 0..31-j with two softmax/O states.
// S^T = mfma(A=K, B=Q) so lane owns q-col (l&31); kv row = (r&3)+8*(r>>2)+4*(l>>5).
// PV: O^T = mfma(A=V^T, B=P). Q already scaled by log2(e)/8 -> exp2-domain softmax.
#define LDK 72
#define DEFER_THR 11.0f

__global__ __launch_bounds__(128) void attn_fwd(const u16* __restrict__ QKV, u16* __restrict__ O) {
  __shared__ __align__(16) u16 Kt[64 * LDK];
  __shared__ __align__(16) u16 Vt[64 * LDK];   // transposed [d][kv]

  const int t = threadIdx.x, l = t & 63, w = t >> 6;
  const int lq = l & 31, hi = l >> 5;
  const int j = blockIdx.x;                    // 0..15
  const int bh = blockIdx.y;                   // 0..63
  const int b = bh >> 4, h = bh & 15;
  const size_t rowb = (size_t)b * 2048;
  const int qcol = h * 64, kcol = 1024 + h * 64, vcol = 2048 + h * 64;
  const int qA0 = 64 * j + 32 * w;             // wave's rows in near tile
  const int qB0 = 64 * (31 - j) + 32 * w;      // wave's rows in far tile
  const int nt = 32 - j;                       // shared KV tiles (64 each)

  short8 qfA[4], qfB[4];
  {
    const u16* qp = QKV + (rowb + qA0 + lq) * 3072 + qcol + hi * 8;
#pragma unroll
    for (int ks = 0; ks < 4; ++ks) qfA[ks] = *reinterpret_cast<const short8*>(qp + ks * 16);
    qp = QKV + (rowb + qB0 + lq) * 3072 + qcol + hi * 8;
#pragma unroll
    for (int ks = 0; ks < 4; ++ks) qfB[ks] = *reinterpret_cast<const short8*>(qp + ks * 16);
  }

  f32x16 oaA[2], oaB[2];
#pragma unroll
  for (int dt = 0; dt < 2; ++dt)
#pragma unroll
    for (int r = 0; r < 16; ++r) { oaA[dt][r] = 0.f; oaB[dt][r] = 0.f; }
  float mA = -1e30f, lA = 0.f, mB = -1e30f, lB = 0.f;

  // staging maps (replicate round-2's measured conflict-free per-wave patterns)
  const int kr = l & 31, kc = ((l >> 5) + 2 * w) * 8;   // K: rows kr/kr+32, cols kc/kc+32
  const int vc = (l & 7) * 8, vp0 = (l >> 3) + 16 * w;  // V: row-pairs vp0, vp0+8; cols vc..vc+7
  short8 ka[4];
  u16x8 vv[4];

  auto stage_load = [&](int kv64) {
    const u16* kp = QKV + (rowb + (size_t)kv64 * 64 + kr) * 3072 + kcol + kc;
    ka[0] = *reinterpret_cast<const short8*>(kp);
    ka[1] = *reinterpret_cast<const short8*>(kp + 32);
    ka[2] = *reinterpret_cast<const short8*>(kp + 32 * 3072);
    ka[3] = *reinterpret_cast<const short8*>(kp + 32 * 3072 + 32);
    const u16* vp = QKV + (rowb + (size_t)kv64 * 64 + 2 * vp0) * 3072 + vcol + vc;
    vv[0] = *reinterpret_cast<const u16x8*>(vp);
    vv[1] = *reinterpret_cast<const u16x8*>(vp + 3072);
    vv[2] = *reinterpret_cast<const u16x8*>(vp + 16 * 3072);
    vv[3] = *reinterpret_cast<const u16x8*>(vp + 17 * 3072);
  };
  auto stage_write = [&]() {
    *reinterpret_cast<short8*>(&Kt[kr * LDK + kc]) = ka[0];
    *reinterpret_cast<short8*>(&Kt[kr * LDK + kc + 32]) = ka[1];
    *reinterpret_cast<short8*>(&Kt[(kr + 32) * LDK + kc]) = ka[2];
    *reinterpret_cast<short8*>(&Kt[(kr + 32) * LDK + kc + 32]) = ka[3];
#pragma unroll
    for (int jj = 0; jj < 8; ++jj) {
      u32 p0 = (u32)vv[0][jj] | ((u32)vv[1][jj] << 16);
      u32 p1 = (u32)vv[2][jj] | ((u32)vv[3][jj] << 16);
      *reinterpret_cast<u32*>(&Vt[(vc + jj) * LDK + 2 * vp0]) = p0;
      *reinterpret_cast<u32*>(&Vt[(vc + jj) * LDK + 2 * (vp0 + 8)]) = p1;
    }
  };

  auto flash = [&](int kv0, int q0, const short8* qf, f32x16* oa, float& m_run, float& l_run,
                   const short8* kf, const short8* vf) {
    f32x16 s;
#pragma unroll
    for (int r = 0; r < 16; ++r) s[r] = 0.f;
#pragma unroll
    for (int ks = 0; ks < 4; ++ks)
      s = __builtin_amdgcn_mfma_f32_32x32x16_bf16(kf[ks], qf[ks], s, 0, 0, 0);
    const bool diag = (kv0 == q0);
    float p[16];
#pragma unroll
    for (int r = 0; r < 16; ++r) {
      float x = s[r];
      if (diag) {
        int off = (r & 3) + 8 * (r >> 2) + 4 * hi;   // kv - kv0
        if (off > lq) x = -1e30f;
      }
      p[r] = x;
    }
    float pm = fmaxf(fmaxf(fmaxf(p[0], p[1]), fmaxf(p[2], p[3])),
                     fmaxf(fmaxf(p[4], p[5]), fmaxf(p[6], p[7])));
    pm = fmaxf(pm, fmaxf(fmaxf(fmaxf(p[8], p[9]), fmaxf(p[10], p[11])),
                         fmaxf(fmaxf(p[12], p[13]), fmaxf(p[14], p[15]))));
    pm = fmaxf(pm, __shfl_xor(pm, 32));
    if (!__all(pm <= m_run + DEFER_THR)) {           // T13 threshold defer
      float mnew = fmaxf(m_run, pm);
      float al = ex2(m_run - mnew);
      l_run *= al;
#pragma unroll
      for (int dt = 0; dt < 2; ++dt)
#pragma unroll
        for (int r = 0; r < 16; ++r) oa[dt][r] *= al;
      m_run = mnew;
    }
    float ps = 0.f;
#pragma unroll
    for (int r = 0; r < 16; ++r) {
      float e = ex2(p[r] - m_run);
      p[r] = e;
      ps += e;
    }
    ps += __shfl_xor(ps, 32);
    l_run += ps;
    // pack P -> bf16 (cvt_pk) + lane-half exchange
    u32 P[8], X[8];
#pragma unroll
    for (int m2 = 0; m2 < 8; ++m2) {
      P[m2] = cvtpk(p[2 * m2], p[2 * m2 + 1]);
      X[m2] = (u32)__shfl_xor((int)P[m2], 32);
    }
    short8 pf[2];
#pragma unroll
    for (int ks2 = 0; ks2 < 2; ++ks2) {
      union { u32 u[4]; short8 v; } uu;
      uu.u[0] = hi ? X[4 * ks2 + 2] : P[4 * ks2 + 0];
      uu.u[1] = hi ? X[4 * ks2 + 3] : P[4 * ks2 + 1];
      uu.u[2] = hi ? P[4 * ks2 + 2] : X[4 * ks2 + 0];
      uu.u[3] = hi ? P[4 * ks2 + 3] : X[4 * ks2 + 1];
      pf[ks2] = uu.v;
    }
#pragma unroll
    for (int ks2 = 0; ks2 < 2; ++ks2)
#pragma unroll
      for (int dt = 0; dt < 2; ++dt)
        oa[dt] = __builtin_amdgcn_mfma_f32_32x32x16_bf16(vf[2 * dt + ks2], pf[ks2], oa[dt], 0, 0, 0);
  };

  // prologue
  stage_load(0);
  stage_write();
  __syncthreads();

  for (int kb = 0; kb < nt; ++kb) {
    if (kb + 1 < nt) stage_load(kb + 1);        // T14: issue loads before compute
#pragma unroll
    for (int kt = 0; kt < 2; ++kt) {
      const int kv0 = kb * 64 + kt * 32;
      short8 kf[4], vf[4];
#pragma unroll
      for (int ks = 0; ks < 4; ++ks)
        kf[ks] = *reinterpret_cast<const short8*>(&Kt[(kt * 32 + lq) * LDK + ks * 16 + hi * 8]);
#pragma unroll
      for (int dt = 0; dt < 2; ++dt)
#pragma unroll
        for (int ks2 = 0; ks2 < 2; ++ks2)
          vf[2 * dt + ks2] = *reinterpret_cast<const short8*>(
              &Vt[(dt * 32 + lq) * LDK + kt * 32 + ks2 * 16 + hi * 8]);
      if (kv0 <= qB0) flash(kv0, qB0, qfB, oaB, mB, lB, kf, vf);
      if (kv0 <= qA0) flash(kv0, qA0, qfA, oaA, mA, lA, kf, vf);
    }
    __syncthreads();
    if (kb + 1 < nt) stage_write();
    __syncthreads();
  }

  // epilogue: normalize, lane-half exchange to d-contiguous chunks, 16B stores
  auto store_o = [&](const f32x16* oa, float l_run, int q0) {
    const float inv = __builtin_amdgcn_rcpf(l_run);
    const size_t obase = (rowb + q0 + lq) * 1024 + h * 64;
#pragma unroll
    for (int dt = 0; dt < 2; ++dt) {
      u32 Bp[8], Xb[8];
#pragma unroll
      for (int m2 = 0; m2 < 8; ++m2) {
        Bp[m2] = cvtpk(oa[dt][2 * m2] * inv, oa[dt][2 * m2 + 1] * inv);
        Xb[m2] = (u32)__shfl_xor((int)Bp[m2], 32);
      }
      if (hi == dt) {
#pragma unroll
        for (int c = 0; c < 4; ++c) {
          union { u32 u[4]; short8 v; } uu;
          uu.u[0] = hi ? Xb[2 * c]     : Bp[2 * c];
          uu.u[1] = hi ? Xb[2 * c + 1] : Bp[2 * c + 1];
          uu.u[2] = hi ? Bp[2 * c]     : Xb[2 * c];
          uu.u[3] = hi ? Bp[2 * c + 1] : Xb[2 * c + 1];
          *reinterpret_cast<short8*>(&O[obase + dt * 32 + c * 8]) = uu.v;
        }
      }
    }
  };
  store_o(oaA, lA, qA0);
  store_o(oaB, lB, qB0);
}

// ---------------- host launch ----------------
extern "C" void kernel_launch(void* const* d_in, const int* in_sizes, int n_in,
                              void* d_out, int out_size, void* d_ws, size_t ws_size,
                              hipStream_t stream) {
  const float* q  = (const float*)d_in[0];
  const float* k  = (const float*)d_in[1];
  const float* v  = (const float*)d_in[2];
  // d_in[3] = mask: known causal tril -> applied analytically
  const float* wq = (const float*)d_in[4];
  const float* bq = (const float*)d_in[5];
  const float* wk = (const float*)d_in[6];
  const float* bk = (const float*)d_in[7];
  const float* wv = (const float*)d_in[8];
  const float* bv = (const float*)d_in[9];
  const float* wo = (const float*)d_in[10];
  const float* bo = (const float*)d_in[11];
  float* out = (float*)d_out;

  u16* ws = (u16*)d_ws;
  const size_t NE = 8192ull * 1024;
  const size_t WE = 1024ull * 1024;
  u16* Xq   = ws;
  u16* Xk   = Xq + NE;
  u16* Xv   = Xk + NE;
  u16* Wq   = Xv + NE;
  u16* Wk   = Wq + WE;
  u16* Wv   = Wk + WE;
  u16* Wo   = Wv + WE;
  u16* QKVp = Wo + WE;                  // [8192][3072]
  u16* AO   = QKVp + 8192ull * 3072;    // [8192][1024]

  cvt3<<<dim3(8192, 3), 256, 0, stream>>>(q, k, v, Xq, Xk, Xv, (int)(NE / 4));
  cvt4<<<dim3(1024, 4), 256, 0, stream>>>(wq, wk, wv, wo, Wq, Wk, Wv, Wo, (int)(WE / 4));

  gemm_qkv<<<dim3(8, 64, 3), 256, 0, stream>>>(Xq, Xk, Xv, Wq, Wk, Wv, bq, bk, bv, QKVp);

  attn_fwd<<<dim3(16, 64), 128, 0, stream>>>(QKVp, AO);

  gemm_out<<<dim3(8, 64), 256, 0, stream>>>(AO, Wo, bo, out);
}

// Round 4
// 409.888 us; speedup vs baseline: 1.4781x; 1.1257x over previous
//
#include <hip/hip_runtime.h>

typedef unsigned short u16;
typedef unsigned int u32;
typedef short short8 __attribute__((ext_vector_type(8)));
typedef u16 u16x8 __attribute__((ext_vector_type(8)));
typedef u16 u16x4 __attribute__((ext_vector_type(4)));
typedef float f32x4 __attribute__((ext_vector_type(4)));
typedef float f32x16 __attribute__((ext_vector_type(16)));

__device__ __forceinline__ u16 f2bf(float f) {
  u32 u = __builtin_bit_cast(u32, f);
  u += 0x7fff + ((u >> 16) & 1);   // RNE
  return (u16)(u >> 16);
}
__device__ __forceinline__ float ex2(float x) {      // 2^x, single v_exp_f32
  float r; asm("v_exp_f32 %0, %1" : "=v"(r) : "v"(x)); return r;
}
__device__ __forceinline__ u32 cvtpk(float lo, float hi) {   // packed bf16
  u32 r; asm("v_cvt_pk_bf16_f32 %0, %1, %2" : "=v"(r) : "v"(lo), "v"(hi)); return r;
}

// async global->LDS 16B (m97 idiom). LDS dest = wave-uniform base + lane*16.
__device__ __forceinline__ void gload16(const u16* g, u16* l) {
  __builtin_amdgcn_global_load_lds(
      (const __attribute__((address_space(1))) u32*)(unsigned long long)(const void*)g,
      (__attribute__((address_space(3))) u32*)(u32)(unsigned long long)(void*)l,
      16, 0, 0);
}

// ---------------- fused f32 -> bf16 converts ----------------
__global__ __launch_bounds__(256) void cvt3(const float* __restrict__ a, const float* __restrict__ b,
                                            const float* __restrict__ c, u16* __restrict__ oa,
                                            u16* __restrict__ ob, u16* __restrict__ oc, int n4) {
  const int z = blockIdx.y;
  const float* s = z == 0 ? a : (z == 1 ? b : c);
  u16* d = z == 0 ? oa : (z == 1 ? ob : oc);
  int i = blockIdx.x * 256 + threadIdx.x;
  if (i >= n4) return;
  float4 f = reinterpret_cast<const float4*>(s)[i];
  u16x4 o;
  o.x = f2bf(f.x); o.y = f2bf(f.y); o.z = f2bf(f.z); o.w = f2bf(f.w);
  reinterpret_cast<u16x4*>(d)[i] = o;
}

__global__ __launch_bounds__(256) void cvt4(const float* __restrict__ a, const float* __restrict__ b,
                                            const float* __restrict__ c, const float* __restrict__ d0,
                                            u16* __restrict__ oa, u16* __restrict__ ob,
                                            u16* __restrict__ oc, u16* __restrict__ od, int n4) {
  const int z = blockIdx.y;
  const float* s = z == 0 ? a : (z == 1 ? b : (z == 2 ? c : d0));
  u16* d = z == 0 ? oa : (z == 1 ? ob : (z == 2 ? oc : od));
  int i = blockIdx.x * 256 + threadIdx.x;
  if (i >= n4) return;
  float4 f = reinterpret_cast<const float4*>(s)[i];
  u16x4 o;
  o.x = f2bf(f.x); o.y = f2bf(f.y); o.z = f2bf(f.z); o.w = f2bf(f.w);
  reinterpret_cast<u16x4*>(d)[i] = o;
}

// ---------------- GEMM: C = A * B^T + bias, scaled. 128x128 tile ----------------
// Minimum-2-phase pipeline (T3-lite): dbuf LDS, per iter {stage next -> compute cur
// -> one barrier}. Loads stay in flight across the MFMA stretch.
__device__ __forceinline__ void gemm_core(const u16* __restrict__ A, const u16* __restrict__ Bm,
                                          const float* __restrict__ bias, u16* __restrict__ Cb,
                                          float* __restrict__ Cf, int K, int ldc, int ccol0,
                                          float cs) {
  __shared__ __align__(16) u16 As[2][128 * 32];
  __shared__ __align__(16) u16 Bs[2][128 * 32];
  const int t = threadIdx.x, l = t & 63, w = t >> 6;
  const int lg = l >> 4, lr = l & 15;
  const int m0 = blockIdx.y * 128, n0 = blockIdx.x * 128;
  const int wr = (w >> 1) * 64, wc = (w & 1) * 64;
  const int srow = w * 32 + (l >> 2);
  const int scol = ((l & 3) ^ ((l >> 2) & 3)) * 8;   // pre-swizzled source chunk
  const u16* ga = A + (size_t)(m0 + srow) * K + scol;
  const u16* gb = Bm + (size_t)(n0 + srow) * K + scol;
  const int ldst = w * 1024 + l * 8;                 // linear dest
  const int ko = (lg ^ (lr & 3)) * 8;                // swizzled frag chunk

  f32x4 acc[4][4];
#pragma unroll
  for (int i = 0; i < 4; ++i)
#pragma unroll
    for (int jj = 0; jj < 4; ++jj) acc[i][jj] = (f32x4){0.f, 0.f, 0.f, 0.f};

  // prologue: stage k-step 0 into buf 0
  gload16(ga, &As[0][ldst]);
  gload16(ga + 16 * (size_t)K, &As[0][ldst + 512]);
  gload16(gb, &Bs[0][ldst]);
  gload16(gb + 16 * (size_t)K, &Bs[0][ldst + 512]);
  __syncthreads();

  const int ni = K >> 5;
  for (int it = 0; it < ni; ++it) {
    const int cur = it & 1;
    if (it + 1 < ni) {                 // issue next-tile loads FIRST (overlap MFMA)
      const int k1 = (it + 1) << 5;
      gload16(ga + k1, &As[cur ^ 1][ldst]);
      gload16(ga + k1 + 16 * (size_t)K, &As[cur ^ 1][ldst + 512]);
      gload16(gb + k1, &Bs[cur ^ 1][ldst]);
      gload16(gb + k1 + 16 * (size_t)K, &Bs[cur ^ 1][ldst + 512]);
    }
    short8 af[4], bf[4];
#pragma unroll
    for (int i = 0; i < 4; ++i)
      af[i] = *reinterpret_cast<const short8*>(&As[cur][(wr + 16 * i + lr) * 32 + ko]);
#pragma unroll
    for (int jj = 0; jj < 4; ++jj)
      bf[jj] = *reinterpret_cast<const short8*>(&Bs[cur][(wc + 16 * jj + lr) * 32 + ko]);
#pragma unroll
    for (int i = 0; i < 4; ++i)
#pragma unroll
      for (int jj = 0; jj < 4; ++jj)
        acc[i][jj] = __builtin_amdgcn_mfma_f32_16x16x32_bf16(af[i], bf[jj], acc[i][jj], 0, 0, 0);
    __syncthreads();                   // one barrier per iter (drains vmcnt+lgkmcnt)
  }

  // C layout (16x16x32): col=lane&15, row=(lane>>4)*4+r  [m89/m91]
#pragma unroll
  for (int i = 0; i < 4; ++i) {
#pragma unroll
    for (int jj = 0; jj < 4; ++jj) {
      int col = n0 + wc + 16 * jj + lr;
      float bv = bias[col];
#pragma unroll
      for (int r = 0; r < 4; ++r) {
        int row = m0 + wr + 16 * i + lg * 4 + r;
        float val = (acc[i][jj][r] + bv) * cs;
        if (Cb) Cb[(size_t)row * ldc + ccol0 + col] = f2bf(val);
        else    Cf[(size_t)row * ldc + col] = val;
      }
    }
  }
}

// Q output pre-scaled by log2(e)/8 so attention softmax runs in exp2 domain.
#define QSCALE 0.18033688011112042f

__global__ __launch_bounds__(256) void gemm_qkv(const u16* __restrict__ Xq, const u16* __restrict__ Xk,
                                                const u16* __restrict__ Xv, const u16* __restrict__ Wq,
                                                const u16* __restrict__ Wk, const u16* __restrict__ Wv,
                                                const float* __restrict__ bq, const float* __restrict__ bk,
                                                const float* __restrict__ bv, u16* __restrict__ QKV) {
  const int z = blockIdx.z;
  const u16* A = z == 0 ? Xq : (z == 1 ? Xk : Xv);
  const u16* B = z == 0 ? Wq : (z == 1 ? Wk : Wv);
  const float* bias = z == 0 ? bq : (z == 1 ? bk : bv);
  gemm_core(A, B, bias, QKV, nullptr, 1024, 3072, z * 1024, z == 0 ? QSCALE : 1.0f);
}

__global__ __launch_bounds__(256) void gemm_out(const u16* __restrict__ AO, const u16* __restrict__ Wo,
                                                const float* __restrict__ bo, float* __restrict__ out) {
  gemm_core(AO, Wo, bo, nullptr, out, 1024, 1024, 0, 1.0f);
}

// ---------------- Flash attention (causal), 64-row blocks, 2 waves ----------------
// Block (bh, iq): qb = 31-iq (LPT: longest first). Wave w owns q rows qb*64+32w..+31.
// S^T = mfma(A=K, B=Q): lane owns q-col (l&31); kv row = (r&3)+8*(r>>2)+4*(l>>5).
// PV: O^T = mfma(A=V^T, B=P). Q pre-scaled by log2(e)/8 -> exp2-domain softmax.
#define LDK 72
#define DEFER_THR 11.0f

__global__ __launch_bounds__(128, 4) void attn_fwd(const u16* __restrict__ QKV, u16* __restrict__ O) {
  __shared__ __align__(16) u16 Kt[64 * LDK];
  __shared__ __align__(16) u16 Vt[64 * LDK];   // transposed [d][kv]

  const int t = threadIdx.x, l = t & 63, w = t >> 6;
  const int lq = l & 31, hi = l >> 5;
  const int bh = blockIdx.x;                   // 0..63
  const int qb = 31 - (int)blockIdx.y;         // 31..0, longest blocks dispatched first
  const int b = bh >> 4, h = bh & 15;
  const size_t rowb = (size_t)b * 2048;
  const int qcol = h * 64, kcol = 1024 + h * 64, vcol = 2048 + h * 64;
  const int q0w = qb * 64 + 32 * w;            // this wave's 32 q rows
  const int nt = qb + 1;                       // KV tiles of 64

  short8 qf[4];
  {
    const u16* qp = QKV + (rowb + q0w + lq) * 3072 + qcol + hi * 8;
#pragma unroll
    for (int ks = 0; ks < 4; ++ks) qf[ks] = *reinterpret_cast<const short8*>(qp + ks * 16);
  }

  f32x16 oa[2];
#pragma unroll
  for (int dt = 0; dt < 2; ++dt)
#pragma unroll
    for (int r = 0; r < 16; ++r) oa[dt][r] = 0.f;
  float m_run = -1e30f, l_run = 0.f;

  // staging maps: exact extension of round-2's measured-0-conflict patterns
  const int kr = t & 31;             // K rows kr, kr+32
  const int kc = (t >> 5) * 8;       // K col groups kc, kc+32   (t>>5 in 0..3)
  const int vr = (t >> 3) * 2;       // V row pairs vr,vr+1 and +32  (t>>3 in 0..15)
  const int vc = (t & 7) * 8;        // V cols vc..vc+7
  short8 ka[4];
  u16x8 vv[4];

  auto stage_load = [&](int kv64) {
    const u16* kp = QKV + (rowb + (size_t)kv64 * 64 + kr) * 3072 + kcol + kc;
    ka[0] = *reinterpret_cast<const short8*>(kp);
    ka[1] = *reinterpret_cast<const short8*>(kp + 32);
    ka[2] = *reinterpret_cast<const short8*>(kp + 32 * 3072);
    ka[3] = *reinterpret_cast<const short8*>(kp + 32 * 3072 + 32);
    const u16* vp = QKV + (rowb + (size_t)kv64 * 64 + vr) * 3072 + vcol + vc;
    vv[0] = *reinterpret_cast<const u16x8*>(vp);
    vv[1] = *reinterpret_cast<const u16x8*>(vp + 3072);
    vv[2] = *reinterpret_cast<const u16x8*>(vp + 32 * 3072);
    vv[3] = *reinterpret_cast<const u16x8*>(vp + 33 * 3072);
  };
  auto stage_write = [&]() {
    *reinterpret_cast<short8*>(&Kt[kr * LDK + kc]) = ka[0];
    *reinterpret_cast<short8*>(&Kt[kr * LDK + kc + 32]) = ka[1];
    *reinterpret_cast<short8*>(&Kt[(kr + 32) * LDK + kc]) = ka[2];
    *reinterpret_cast<short8*>(&Kt[(kr + 32) * LDK + kc + 32]) = ka[3];
#pragma unroll
    for (int jj = 0; jj < 8; ++jj) {
      u32 p0 = (u32)vv[0][jj] | ((u32)vv[1][jj] << 16);
      u32 p1 = (u32)vv[2][jj] | ((u32)vv[3][jj] << 16);
      *reinterpret_cast<u32*>(&Vt[(vc + jj) * LDK + vr]) = p0;
      *reinterpret_cast<u32*>(&Vt[(vc + jj) * LDK + vr + 32]) = p1;
    }
  };

  auto flash = [&](int kv0) {
    short8 kf[4], vf[4];
    const int kt32 = (kv0 & 63);     // 0 or 32 within tile
#pragma unroll
    for (int ks = 0; ks < 4; ++ks)
      kf[ks] = *reinterpret_cast<const short8*>(&Kt[(kt32 + lq) * LDK + ks * 16 + hi * 8]);
#pragma unroll
    for (int dt = 0; dt < 2; ++dt)
#pragma unroll
      for (int ks2 = 0; ks2 < 2; ++ks2)
        vf[2 * dt + ks2] = *reinterpret_cast<const short8*>(
            &Vt[(dt * 32 + lq) * LDK + kt32 + ks2 * 16 + hi * 8]);
    f32x16 s;
#pragma unroll
    for (int r = 0; r < 16; ++r) s[r] = 0.f;
    __builtin_amdgcn_s_setprio(1);
#pragma unroll
    for (int ks = 0; ks < 4; ++ks)
      s = __builtin_amdgcn_mfma_f32_32x32x16_bf16(kf[ks], qf[ks], s, 0, 0, 0);
    __builtin_amdgcn_s_setprio(0);
    const bool diag = (kv0 == q0w);
    float p[16];
#pragma unroll
    for (int r = 0; r < 16; ++r) {
      float x = s[r];
      if (diag) {
        int off = (r & 3) + 8 * (r >> 2) + 4 * hi;   // kv - kv0
        if (off > lq) x = -1e30f;
      }
      p[r] = x;
    }
    float pm = fmaxf(fmaxf(fmaxf(p[0], p[1]), fmaxf(p[2], p[3])),
                     fmaxf(fmaxf(p[4], p[5]), fmaxf(p[6], p[7])));
    pm = fmaxf(pm, fmaxf(fmaxf(fmaxf(p[8], p[9]), fmaxf(p[10], p[11])),
                         fmaxf(fmaxf(p[12], p[13]), fmaxf(p[14], p[15]))));
    pm = fmaxf(pm, __shfl_xor(pm, 32));
    if (!__all(pm <= m_run + DEFER_THR)) {           // T13 threshold defer
      float mnew = fmaxf(m_run, pm);
      float al = ex2(m_run - mnew);
      l_run *= al;
#pragma unroll
      for (int dt = 0; dt < 2; ++dt)
#pragma unroll
        for (int r = 0; r < 16; ++r) oa[dt][r] *= al;
      m_run = mnew;
    }
    float ps = 0.f;
#pragma unroll
    for (int r = 0; r < 16; ++r) {
      float e = ex2(p[r] - m_run);
      p[r] = e;
      ps += e;
    }
    ps += __shfl_xor(ps, 32);
    l_run += ps;
    // pack P -> bf16 (cvt_pk) + lane-half exchange
    u32 P[8], X[8];
#pragma unroll
    for (int m2 = 0; m2 < 8; ++m2) {
      P[m2] = cvtpk(p[2 * m2], p[2 * m2 + 1]);
      X[m2] = (u32)__shfl_xor((int)P[m2], 32);
    }
    short8 pf[2];
#pragma unroll
    for (int ks2 = 0; ks2 < 2; ++ks2) {
      union { u32 u[4]; short8 v; } uu;
      uu.u[0] = hi ? X[4 * ks2 + 2] : P[4 * ks2 + 0];
      uu.u[1] = hi ? X[4 * ks2 + 3] : P[4 * ks2 + 1];
      uu.u[2] = hi ? P[4 * ks2 + 2] : X[4 * ks2 + 0];
      uu.u[3] = hi ? P[4 * ks2 + 3] : X[4 * ks2 + 1];
      pf[ks2] = uu.v;
    }
    __builtin_amdgcn_s_setprio(1);
#pragma unroll
    for (int ks2 = 0; ks2 < 2; ++ks2)
#pragma unroll
      for (int dt = 0; dt < 2; ++dt)
        oa[dt] = __builtin_amdgcn_mfma_f32_32x32x16_bf16(vf[2 * dt + ks2], pf[ks2], oa[dt], 0, 0, 0);
    __builtin_amdgcn_s_setprio(0);
  };

  // prologue
  stage_load(0);
  stage_write();
  __syncthreads();

  for (int kb = 0; kb < nt; ++kb) {
    if (kb + 1 < nt) stage_load(kb + 1);        // T14: issue loads before compute
#pragma unroll
    for (int kt = 0; kt < 2; ++kt) {
      const int kv0 = kb * 64 + kt * 32;
      if (kv0 <= q0w) flash(kv0);
    }
    __syncthreads();
    if (kb + 1 < nt) stage_write();
    __syncthreads();
  }

  // epilogue: normalize, lane-half exchange to d-contiguous chunks, 16B stores
  const float inv = __builtin_amdgcn_rcpf(l_run);
  const size_t obase = (rowb + q0w + lq) * 1024 + h * 64;
#pragma unroll
  for (int dt = 0; dt < 2; ++dt) {
    u32 Bp[8], Xb[8];
#pragma unroll
    for (int m2 = 0; m2 < 8; ++m2) {
      Bp[m2] = cvtpk(oa[dt][2 * m2] * inv, oa[dt][2 * m2 + 1] * inv);
      Xb[m2] = (u32)__shfl_xor((int)Bp[m2], 32);
    }
    if (hi == dt) {
#pragma unroll
      for (int c = 0; c < 4; ++c) {
        union { u32 u[4]; short8 v; } uu;
        uu.u[0] = hi ? Xb[2 * c]     : Bp[2 * c];
        uu.u[1] = hi ? Xb[2 * c + 1] : Bp[2 * c + 1];
        uu.u[2] = hi ? Bp[2 * c]     : Xb[2 * c];
        uu.u[3] = hi ? Bp[2 * c + 1] : Xb[2 * c + 1];
        *reinterpret_cast<short8*>(&O[obase + dt * 32 + c * 8]) = uu.v;
      }
    }
  }
}

// ---------------- host launch ----------------
extern "C" void kernel_launch(void* const* d_in, const int* in_sizes, int n_in,
                              void* d_out, int out_size, void* d_ws, size_t ws_size,
                              hipStream_t stream) {
  const float* q  = (const float*)d_in[0];
  const float* k  = (const float*)d_in[1];
  const float* v  = (const float*)d_in[2];
  // d_in[3] = mask: known causal tril -> applied analytically
  const float* wq = (const float*)d_in[4];
  const float* bq = (const float*)d_in[5];
  const float* wk = (const float*)d_in[6];
  const float* bk = (const float*)d_in[7];
  const float* wv = (const float*)d_in[8];
  const float* bv = (const float*)d_in[9];
  const float* wo = (const float*)d_in[10];
  const float* bo = (const float*)d_in[11];
  float* out = (float*)d_out;

  u16* ws = (u16*)d_ws;
  const size_t NE = 8192ull * 1024;
  const size_t WE = 1024ull * 1024;
  u16* Xq   = ws;
  u16* Xk   = Xq + NE;
  u16* Xv   = Xk + NE;
  u16* Wq   = Xv + NE;
  u16* Wk   = Wq + WE;
  u16* Wv   = Wk + WE;
  u16* Wo   = Wv + WE;
  u16* QKVp = Wo + WE;                  // [8192][3072]
  u16* AO   = QKVp + 8192ull * 3072;    // [8192][1024]

  cvt3<<<dim3(8192, 3), 256, 0, stream>>>(q, k, v, Xq, Xk, Xv, (int)(NE / 4));
  cvt4<<<dim3(1024, 4), 256, 0, stream>>>(wq, wk, wv, wo, Wq, Wk, Wv, Wo, (int)(WE / 4));

  gemm_qkv<<<dim3(8, 64, 3), 256, 0, stream>>>(Xq, Xk, Xv, Wq, Wk, Wv, bq, bk, bv, QKVp);

  attn_fwd<<<dim3(64, 32), 128, 0, stream>>>(QKVp, AO);

  gemm_out<<<dim3(8, 64), 256, 0, stream>>>(AO, Wo, bo, out);
}

// Round 5
// 373.911 us; speedup vs baseline: 1.6203x; 1.0962x over previous
//
#include <hip/hip_runtime.h>

typedef unsigned short u16;
typedef unsigned int u32;
typedef short short8 __attribute__((ext_vector_type(8)));
typedef u16 u16x8 __attribute__((ext_vector_type(8)));
typedef u16 u16x4 __attribute__((ext_vector_type(4)));
typedef float f32x4 __attribute__((ext_vector_type(4)));
typedef float f32x16 __attribute__((ext_vector_type(16)));

__device__ __forceinline__ u16 f2bf(float f) {
  u32 u = __builtin_bit_cast(u32, f);
  u += 0x7fff + ((u >> 16) & 1);   // RNE
  return (u16)(u >> 16);
}
__device__ __forceinline__ float ex2(float x) {      // 2^x, single v_exp_f32
  float r; asm("v_exp_f32 %0, %1" : "=v"(r) : "v"(x)); return r;
}
__device__ __forceinline__ u32 cvtpk(float lo, float hi) {   // packed bf16
  u32 r; asm("v_cvt_pk_bf16_f32 %0, %1, %2" : "=v"(r) : "v"(lo), "v"(hi)); return r;
}

// async global->LDS 16B (m97 idiom). LDS dest = wave-uniform base + lane*16.
__device__ __forceinline__ void gload16(const u16* g, u16* l) {
  __builtin_amdgcn_global_load_lds(
      (const __attribute__((address_space(1))) u32*)(unsigned long long)(const void*)g,
      (__attribute__((address_space(3))) u32*)(u32)(unsigned long long)(void*)l,
      16, 0, 0);
}

// ---------------- fused f32 -> bf16 converts ----------------
__global__ __launch_bounds__(256) void cvt3(const float* __restrict__ a, const float* __restrict__ b,
                                            const float* __restrict__ c, u16* __restrict__ oa,
                                            u16* __restrict__ ob, u16* __restrict__ oc, int n4) {
  const int z = blockIdx.y;
  const float* s = z == 0 ? a : (z == 1 ? b : c);
  u16* d = z == 0 ? oa : (z == 1 ? ob : oc);
  int i = blockIdx.x * 256 + threadIdx.x;
  if (i >= n4) return;
  float4 f = reinterpret_cast<const float4*>(s)[i];
  u16x4 o;
  o.x = f2bf(f.x); o.y = f2bf(f.y); o.z = f2bf(f.z); o.w = f2bf(f.w);
  reinterpret_cast<u16x4*>(d)[i] = o;
}

__global__ __launch_bounds__(256) void cvt4(const float* __restrict__ a, const float* __restrict__ b,
                                            const float* __restrict__ c, const float* __restrict__ d0,
                                            u16* __restrict__ oa, u16* __restrict__ ob,
                                            u16* __restrict__ oc, u16* __restrict__ od, int n4) {
  const int z = blockIdx.y;
  const float* s = z == 0 ? a : (z == 1 ? b : (z == 2 ? c : d0));
  u16* d = z == 0 ? oa : (z == 1 ? ob : (z == 2 ? oc : od));
  int i = blockIdx.x * 256 + threadIdx.x;
  if (i >= n4) return;
  float4 f = reinterpret_cast<const float4*>(s)[i];
  u16x4 o;
  o.x = f2bf(f.x); o.y = f2bf(f.y); o.z = f2bf(f.z); o.w = f2bf(f.w);
  reinterpret_cast<u16x4*>(d)[i] = o;
}

// ---------------- GEMM: C = A * B^T + bias. 128x128 tile, BK=32 ----------------
// Counted-vmcnt pipeline (T4): 3 LDS buffers, 2-ahead prefetch, raw s_barrier,
// s_waitcnt vmcnt(4) in steady state (never 0 -> loads span barriers).
// LDS chunk swizzle: logical k-chunk c of row r stored at phys chunk c^((r>>1)&3)
// -> frag reads are 2-way bank aliased (free).
__device__ __forceinline__ void gemm_core(const u16* __restrict__ A, const u16* __restrict__ Bm,
                                          const float* __restrict__ bias, u16* __restrict__ Cb,
                                          float* __restrict__ Cf, int K, int ldc, int ccol0,
                                          float cs) {
  __shared__ __align__(16) u16 As[3][128 * 32];
  __shared__ __align__(16) u16 Bs[3][128 * 32];
  const int t = threadIdx.x, l = t & 63, w = t >> 6;
  const int lg = l >> 4, lr = l & 15;
  const int m0 = blockIdx.y * 128, n0 = blockIdx.x * 128;
  const int wr = (w >> 1) * 64, wc = (w & 1) * 64;
  const int srow = w * 32 + (l >> 2);
  const int scol = ((l & 3) ^ ((l >> 3) & 3)) * 8;   // pre-swizzled source chunk
  const u16* ga = A + (size_t)(m0 + srow) * K + scol;
  const u16* gb = Bm + (size_t)(n0 + srow) * K + scol;
  const int ldst = w * 1024 + l * 8;                 // linear LDS dest (u16)
  const int ko = (lg ^ ((lr >> 1) & 3)) * 8;         // swizzled frag chunk

  u16* a0 = &As[0][0]; u16* a1 = &As[1][0]; u16* a2 = &As[2][0];
  u16* b0 = &Bs[0][0]; u16* b1 = &Bs[1][0]; u16* b2 = &Bs[2][0];

  f32x4 acc[4][4];
#pragma unroll
  for (int i = 0; i < 4; ++i)
#pragma unroll
    for (int jj = 0; jj < 4; ++jj) acc[i][jj] = (f32x4){0.f, 0.f, 0.f, 0.f};

  const int ni = K >> 5;
  // prologue: stage tiles 0,1
  gload16(ga, a0 + ldst);
  gload16(ga + 16 * (size_t)K, a0 + ldst + 512);
  gload16(gb, b0 + ldst);
  gload16(gb + 16 * (size_t)K, b0 + ldst + 512);
  gload16(ga + 32, a1 + ldst);
  gload16(ga + 32 + 16 * (size_t)K, a1 + ldst + 512);
  gload16(gb + 32, b1 + ldst);
  gload16(gb + 32 + 16 * (size_t)K, b1 + ldst + 512);
  asm volatile("s_waitcnt vmcnt(4)" ::: "memory");   // tile 0 landed
  __builtin_amdgcn_s_barrier();
  __builtin_amdgcn_sched_barrier(0);

  for (int it = 0; it < ni; ++it) {
    const bool pf = (it + 2) < ni;
    if (pf) {                       // stage tile it+2 into the rotating 3rd buffer
      const int k2 = (it + 2) << 5;
      gload16(ga + k2, a2 + ldst);
      gload16(ga + k2 + 16 * (size_t)K, a2 + ldst + 512);
      gload16(gb + k2, b2 + ldst);
      gload16(gb + k2 + 16 * (size_t)K, b2 + ldst + 512);
    }
    short8 af[4], bf[4];
#pragma unroll
    for (int i = 0; i < 4; ++i)
      af[i] = *reinterpret_cast<const short8*>(&a0[(wr + 16 * i + lr) * 32 + ko]);
#pragma unroll
    for (int jj = 0; jj < 4; ++jj)
      bf[jj] = *reinterpret_cast<const short8*>(&b0[(wc + 16 * jj + lr) * 32 + ko]);
    __builtin_amdgcn_s_setprio(1);
#pragma unroll
    for (int i = 0; i < 4; ++i)
#pragma unroll
      for (int jj = 0; jj < 4; ++jj)
        acc[i][jj] = __builtin_amdgcn_mfma_f32_16x16x32_bf16(af[i], bf[jj], acc[i][jj], 0, 0, 0);
    __builtin_amdgcn_s_setprio(0);
    if (it + 1 < ni) {
      if (pf) asm volatile("s_waitcnt vmcnt(4)" ::: "memory");  // tile it+1 landed
      else    asm volatile("s_waitcnt vmcnt(0)" ::: "memory");
      __builtin_amdgcn_s_barrier();
      __builtin_amdgcn_sched_barrier(0);
    }
    u16* tmp;
    tmp = a0; a0 = a1; a1 = a2; a2 = tmp;
    tmp = b0; b0 = b1; b1 = b2; b2 = tmp;
  }

  // C layout (16x16x32): col=lane&15, row=(lane>>4)*4+r  [m89/m91]
#pragma unroll
  for (int i = 0; i < 4; ++i) {
#pragma unroll
    for (int jj = 0; jj < 4; ++jj) {
      int col = n0 + wc + 16 * jj + lr;
      float bv = bias[col];
#pragma unroll
      for (int r = 0; r < 4; ++r) {
        int row = m0 + wr + 16 * i + lg * 4 + r;
        float val = (acc[i][jj][r] + bv) * cs;
        if (Cb) Cb[(size_t)row * ldc + ccol0 + col] = f2bf(val);
        else    Cf[(size_t)row * ldc + col] = val;
      }
    }
  }
}

// Q output pre-scaled by log2(e)/8 so attention softmax runs in exp2 domain.
#define QSCALE 0.18033688011112042f

__global__ __launch_bounds__(256) void gemm_qkv(const u16* __restrict__ Xq, const u16* __restrict__ Xk,
                                                const u16* __restrict__ Xv, const u16* __restrict__ Wq,
                                                const u16* __restrict__ Wk, const u16* __restrict__ Wv,
                                                const float* __restrict__ bq, const float* __restrict__ bk,
                                                const float* __restrict__ bv, u16* __restrict__ QKV) {
  const int z = blockIdx.z;
  const u16* A = z == 0 ? Xq : (z == 1 ? Xk : Xv);
  const u16* B = z == 0 ? Wq : (z == 1 ? Wk : Wv);
  const float* bias = z == 0 ? bq : (z == 1 ? bk : bv);
  gemm_core(A, B, bias, QKV, nullptr, 1024, 3072, z * 1024, z == 0 ? QSCALE : 1.0f);
}

__global__ __launch_bounds__(256) void gemm_out(const u16* __restrict__ AO, const u16* __restrict__ Wo,
                                                const float* __restrict__ bo, float* __restrict__ out) {
  gemm_core(AO, Wo, bo, nullptr, out, 1024, 1024, 0, 1.0f);
}

// ---------------- Flash attention (causal), 128-row blocks, 4 waves ----------------
// Block (bh, iq): qb = 15-iq (LPT). Wave w owns q rows qb*128+32w..+31.
// KV tile 64 staged once for 4 waves; round-2's measured-0-conflict staging maps.
// S^T = mfma(A=K, B=Q): lane owns q-col (l&31); kv row = (r&3)+8*(r>>2)+4*(l>>5).
// PV: O^T = mfma(A=V^T, B=P). Q pre-scaled by log2(e)/8 -> exp2-domain softmax.
#define LDK 72
#define DEFER_THR 11.0f

__global__ __launch_bounds__(256, 4) void attn_fwd(const u16* __restrict__ QKV, u16* __restrict__ O) {
  __shared__ __align__(16) u16 Kt[64 * LDK];
  __shared__ __align__(16) u16 Vt[64 * LDK];   // transposed [d][kv]

  const int t = threadIdx.x, l = t & 63, w = t >> 6;
  const int lq = l & 31, hi = l >> 5;
  const int bh = blockIdx.x;                   // 0..63
  const int qb = 15 - (int)blockIdx.y;         // 15..0, longest blocks first
  const int b = bh >> 4, h = bh & 15;
  const size_t rowb = (size_t)b * 2048;
  const int qcol = h * 64, kcol = 1024 + h * 64, vcol = 2048 + h * 64;
  const int q0w = qb * 128 + 32 * w;           // this wave's 32 q rows
  const int nt = 2 * qb + 2;                   // KV tiles of 64

  short8 qf[4];
  {
    const u16* qp = QKV + (rowb + q0w + lq) * 3072 + qcol + hi * 8;
#pragma unroll
    for (int ks = 0; ks < 4; ++ks) qf[ks] = *reinterpret_cast<const short8*>(qp + ks * 16);
  }

  f32x16 oa[2];
#pragma unroll
  for (int dt = 0; dt < 2; ++dt)
#pragma unroll
    for (int r = 0; r < 16; ++r) oa[dt][r] = 0.f;
  float m_run = -1e30f, l_run = 0.f;

  // staging maps (round-2 verbatim, measured 0 conflicts with 256 threads):
  // K: rows kr,kr+32 cols kc..kc+7; V: row-pairs 2kr,2kr+1 cols kc..kc+7
  const int kr = t & 31, kc = (t >> 5) * 8;    // t>>5 in 0..7
  short8 ka0, ka1;
  u16x8 va0, va1;

  auto stage_load = [&](int kv64) {
    const u16* kp = QKV + (rowb + (size_t)kv64 * 64 + kr) * 3072 + kcol + kc;
    ka0 = *reinterpret_cast<const short8*>(kp);
    ka1 = *reinterpret_cast<const short8*>(kp + 32 * 3072);
    const u16* vp = QKV + (rowb + (size_t)kv64 * 64 + 2 * kr) * 3072 + vcol + kc;
    va0 = *reinterpret_cast<const u16x8*>(vp);
    va1 = *reinterpret_cast<const u16x8*>(vp + 3072);
  };
  auto stage_write = [&]() {
    *reinterpret_cast<short8*>(&Kt[kr * LDK + kc]) = ka0;
    *reinterpret_cast<short8*>(&Kt[(kr + 32) * LDK + kc]) = ka1;
#pragma unroll
    for (int jj = 0; jj < 8; ++jj) {
      u32 pk = (u32)va0[jj] | ((u32)va1[jj] << 16);
      *reinterpret_cast<u32*>(&Vt[(kc + jj) * LDK + 2 * kr]) = pk;
    }
  };

  auto flash = [&](int kv0) {
    short8 kf[4], vf[4];
    const int kt32 = (kv0 & 63);     // 0 or 32 within tile
#pragma unroll
    for (int ks = 0; ks < 4; ++ks)
      kf[ks] = *reinterpret_cast<const short8*>(&Kt[(kt32 + lq) * LDK + ks * 16 + hi * 8]);
#pragma unroll
    for (int dt = 0; dt < 2; ++dt)
#pragma unroll
      for (int ks2 = 0; ks2 < 2; ++ks2)
        vf[2 * dt + ks2] = *reinterpret_cast<const short8*>(
            &Vt[(dt * 32 + lq) * LDK + kt32 + ks2 * 16 + hi * 8]);
    f32x16 s;
#pragma unroll
    for (int r = 0; r < 16; ++r) s[r] = 0.f;
    __builtin_amdgcn_s_setprio(1);
#pragma unroll
    for (int ks = 0; ks < 4; ++ks)
      s = __builtin_amdgcn_mfma_f32_32x32x16_bf16(kf[ks], qf[ks], s, 0, 0, 0);
    __builtin_amdgcn_s_setprio(0);
    const bool diag = (kv0 == q0w);
    float p[16];
#pragma unroll
    for (int r = 0; r < 16; ++r) {
      float x = s[r];
      if (diag) {
        int off = (r & 3) + 8 * (r >> 2) + 4 * hi;   // kv - kv0
        if (off > lq) x = -1e30f;
      }
      p[r] = x;
    }
    float pm = fmaxf(fmaxf(fmaxf(p[0], p[1]), fmaxf(p[2], p[3])),
                     fmaxf(fmaxf(p[4], p[5]), fmaxf(p[6], p[7])));
    pm = fmaxf(pm, fmaxf(fmaxf(fmaxf(p[8], p[9]), fmaxf(p[10], p[11])),
                         fmaxf(fmaxf(p[12], p[13]), fmaxf(p[14], p[15]))));
    pm = fmaxf(pm, __shfl_xor(pm, 32));
    if (!__all(pm <= m_run + DEFER_THR)) {           // T13 threshold defer
      float mnew = fmaxf(m_run, pm);
      float al = ex2(m_run - mnew);
      l_run *= al;
#pragma unroll
      for (int dt = 0; dt < 2; ++dt)
#pragma unroll
        for (int r = 0; r < 16; ++r) oa[dt][r] *= al;
      m_run = mnew;
    }
    float ps = 0.f;
#pragma unroll
    for (int r = 0; r < 16; ++r) {
      float e = ex2(p[r] - m_run);
      p[r] = e;
      ps += e;
    }
    ps += __shfl_xor(ps, 32);
    l_run += ps;
    // pack P -> bf16 (cvt_pk) + lane-half exchange
    u32 P[8], X[8];
#pragma unroll
    for (int m2 = 0; m2 < 8; ++m2) {
      P[m2] = cvtpk(p[2 * m2], p[2 * m2 + 1]);
      X[m2] = (u32)__shfl_xor((int)P[m2], 32);
    }
    short8 pf[2];
#pragma unroll
    for (int ks2 = 0; ks2 < 2; ++ks2) {
      union { u32 u[4]; short8 v; } uu;
      uu.u[0] = hi ? X[4 * ks2 + 2] : P[4 * ks2 + 0];
      uu.u[1] = hi ? X[4 * ks2 + 3] : P[4 * ks2 + 1];
      uu.u[2] = hi ? P[4 * ks2 + 2] : X[4 * ks2 + 0];
      uu.u[3] = hi ? P[4 * ks2 + 3] : X[4 * ks2 + 1];
      pf[ks2] = uu.v;
    }
    __builtin_amdgcn_s_setprio(1);
#pragma unroll
    for (int ks2 = 0; ks2 < 2; ++ks2)
#pragma unroll
      for (int dt = 0; dt < 2; ++dt)
        oa[dt] = __builtin_amdgcn_mfma_f32_32x32x16_bf16(vf[2 * dt + ks2], pf[ks2], oa[dt], 0, 0, 0);
    __builtin_amdgcn_s_setprio(0);
  };

  // prologue
  stage_load(0);
  stage_write();
  __syncthreads();

  for (int kb = 0; kb < nt; ++kb) {
    if (kb + 1 < nt) stage_load(kb + 1);        // T14: issue loads before compute
#pragma unroll
    for (int kt = 0; kt < 2; ++kt) {
      const int kv0 = kb * 64 + kt * 32;
      if (kv0 <= q0w) flash(kv0);
    }
    __syncthreads();
    if (kb + 1 < nt) stage_write();
    __syncthreads();
  }

  // epilogue: normalize, lane-half exchange to d-contiguous chunks, 16B stores
  const float inv = __builtin_amdgcn_rcpf(l_run);
  const size_t obase = (rowb + q0w + lq) * 1024 + h * 64;
#pragma unroll
  for (int dt = 0; dt < 2; ++dt) {
    u32 Bp[8], Xb[8];
#pragma unroll
    for (int m2 = 0; m2 < 8; ++m2) {
      Bp[m2] = cvtpk(oa[dt][2 * m2] * inv, oa[dt][2 * m2 + 1] * inv);
      Xb[m2] = (u32)__shfl_xor((int)Bp[m2], 32);
    }
    if (hi == dt) {
#pragma unroll
      for (int c = 0; c < 4; ++c) {
        union { u32 u[4]; short8 v; } uu;
        uu.u[0] = hi ? Xb[2 * c]     : Bp[2 * c];
        uu.u[1] = hi ? Xb[2 * c + 1] : Bp[2 * c + 1];
        uu.u[2] = hi ? Bp[2 * c]     : Xb[2 * c];
        uu.u[3] = hi ? Bp[2 * c + 1] : Xb[2 * c + 1];
        *reinterpret_cast<short8*>(&O[obase + dt * 32 + c * 8]) = uu.v;
      }
    }
  }
}

// ---------------- host launch ----------------
extern "C" void kernel_launch(void* const* d_in, const int* in_sizes, int n_in,
                              void* d_out, int out_size, void* d_ws, size_t ws_size,
                              hipStream_t stream) {
  const float* q  = (const float*)d_in[0];
  const float* k  = (const float*)d_in[1];
  const float* v  = (const float*)d_in[2];
  // d_in[3] = mask: known causal tril -> applied analytically
  const float* wq = (const float*)d_in[4];
  const float* bq = (const float*)d_in[5];
  const float* wk = (const float*)d_in[6];
  const float* bk = (const float*)d_in[7];
  const float* wv = (const float*)d_in[8];
  const float* bv = (const float*)d_in[9];
  const float* wo = (const float*)d_in[10];
  const float* bo = (const float*)d_in[11];
  float* out = (float*)d_out;

  u16* ws = (u16*)d_ws;
  const size_t NE = 8192ull * 1024;
  const size_t WE = 1024ull * 1024;
  u16* Xq   = ws;
  u16* Xk   = Xq + NE;
  u16* Xv   = Xk + NE;
  u16* Wq   = Xv + NE;
  u16* Wk   = Wq + WE;
  u16* Wv   = Wk + WE;
  u16* Wo   = Wv + WE;
  u16* QKVp = Wo + WE;                  // [8192][3072]
  u16* AO   = QKVp + 8192ull * 3072;    // [8192][1024]

  cvt3<<<dim3(8192, 3), 256, 0, stream>>>(q, k, v, Xq, Xk, Xv, (int)(NE / 4));
  cvt4<<<dim3(1024, 4), 256, 0, stream>>>(wq, wk, wv, wo, Wq, Wk, Wv, Wo, (int)(WE / 4));

  gemm_qkv<<<dim3(8, 64, 3), 256, 0, stream>>>(Xq, Xk, Xv, Wq, Wk, Wv, bq, bk, bv, QKVp);

  attn_fwd<<<dim3(64, 16), 256, 0, stream>>>(QKVp, AO);

  gemm_out<<<dim3(8, 64), 256, 0, stream>>>(AO, Wo, bo, out);
}

// Round 6
// 356.941 us; speedup vs baseline: 1.6974x; 1.0475x over previous
//
#include <hip/hip_runtime.h>

typedef unsigned short u16;
typedef unsigned int u32;
typedef short short8 __attribute__((ext_vector_type(8)));
typedef u16 u16x8 __attribute__((ext_vector_type(8)));
typedef u16 u16x4 __attribute__((ext_vector_type(4)));
typedef float f32x4 __attribute__((ext_vector_type(4)));
typedef float f32x16 __attribute__((ext_vector_type(16)));

__device__ __forceinline__ u16 f2bf(float f) {
  u32 u = __builtin_bit_cast(u32, f);
  u += 0x7fff + ((u >> 16) & 1);   // RNE
  return (u16)(u >> 16);
}
__device__ __forceinline__ float ex2(float x) {      // 2^x, single v_exp_f32
  float r; asm("v_exp_f32 %0, %1" : "=v"(r) : "v"(x)); return r;
}
__device__ __forceinline__ u32 cvtpk(float lo, float hi) {   // packed bf16
  u32 r; asm("v_cvt_pk_bf16_f32 %0, %1, %2" : "=v"(r) : "v"(lo), "v"(hi)); return r;
}

// async global->LDS 16B (m97 idiom). LDS dest = wave-uniform base + lane*16.
__device__ __forceinline__ void gload16(const u16* g, u16* l) {
  __builtin_amdgcn_global_load_lds(
      (const __attribute__((address_space(1))) u32*)(unsigned long long)(const void*)g,
      (__attribute__((address_space(3))) u32*)(u32)(unsigned long long)(void*)l,
      16, 0, 0);
}

// ---------------- single-launch f32 -> bf16 convert for all 7 arrays ----------------
#define NB 8192   // blocks per big array (8M elems / 1024)
#define WB 1024   // blocks per weight array (1M elems / 1024)

__global__ __launch_bounds__(256) void cvt_all(
    const float* __restrict__ q, const float* __restrict__ k, const float* __restrict__ v,
    const float* __restrict__ wq, const float* __restrict__ wk, const float* __restrict__ wv,
    const float* __restrict__ wo, u16* __restrict__ Xq, u16* __restrict__ Xk,
    u16* __restrict__ Xv, u16* __restrict__ Wq, u16* __restrict__ Wk, u16* __restrict__ Wv,
    u16* __restrict__ Wo) {
  int bid = blockIdx.x;
  const float* s; u16* d; int x;
  if (bid < 3 * NB) {
    int z = bid / NB; x = bid - z * NB;
    s = z == 0 ? q : (z == 1 ? k : v);
    d = z == 0 ? Xq : (z == 1 ? Xk : Xv);
  } else {
    int r = bid - 3 * NB;
    int z = r / WB; x = r - z * WB;
    s = z == 0 ? wq : (z == 1 ? wk : (z == 2 ? wv : wo));
    d = z == 0 ? Wq : (z == 1 ? Wk : (z == 2 ? Wv : Wo));
  }
  int i = x * 256 + threadIdx.x;
  float4 f = reinterpret_cast<const float4*>(s)[i];
  u16x4 o;
  o.x = f2bf(f.x); o.y = f2bf(f.y); o.z = f2bf(f.z); o.w = f2bf(f.w);
  reinterpret_cast<u16x4*>(d)[i] = o;
}

// ---------------- GEMM: C = A * B^T + bias. BMx128 tile, BK=32 ----------------
// Counted-vmcnt pipeline: 3 LDS buffers, 2-ahead prefetch, raw s_barrier,
// steady-state wait leaves one tile's loads in flight (never vmcnt(0) mid-loop).
// LDS chunk swizzle: logical k-chunk c of row r stored at phys c^((r>>1)&3).
template <int BM>
__device__ __forceinline__ void gemm_core(const u16* __restrict__ A, const u16* __restrict__ Bm,
                                          const float* __restrict__ bias, u16* __restrict__ Cb,
                                          float* __restrict__ Cf, int K, int ldc, int ccol0,
                                          float cs) {
  constexpr int MI = BM / 32;                  // row frags per wave (4 or 2)
  __shared__ __align__(16) u16 As[3][BM * 32];
  __shared__ __align__(16) u16 Bs[3][128 * 32];
  const int t = threadIdx.x, l = t & 63, w = t >> 6;
  const int lg = l >> 4, lr = l & 15;
  const int m0 = blockIdx.y * BM, n0 = blockIdx.x * 128;
  const int wr = (w >> 1) * (16 * MI), wc = (w & 1) * 64;
  const int srowA = (BM == 128) ? (w * 32 + (l >> 2)) : (w * 16 + (l >> 2));
  const int srowB = w * 32 + (l >> 2);
  const int scol = ((l & 3) ^ ((l >> 3) & 3)) * 8;   // pre-swizzled source chunk
  const u16* ga = A + (size_t)(m0 + srowA) * K + scol;
  const u16* gb = Bm + (size_t)(n0 + srowB) * K + scol;
  const int ldstA = (BM == 128) ? (w * 1024 + l * 8) : (w * 512 + l * 8);
  const int ldstB = w * 1024 + l * 8;
  const int ko = (lg ^ ((lr >> 1) & 3)) * 8;         // swizzled frag chunk

  u16* a0 = &As[0][0]; u16* a1 = &As[1][0]; u16* a2 = &As[2][0];
  u16* b0 = &Bs[0][0]; u16* b1 = &Bs[1][0]; u16* b2 = &Bs[2][0];

  auto stage = [&](int kk, u16* ab, u16* bb) {
    gload16(ga + kk, ab + ldstA);
    if constexpr (BM == 128) gload16(ga + kk + 16 * (size_t)K, ab + ldstA + 512);
    gload16(gb + kk, bb + ldstB);
    gload16(gb + kk + 16 * (size_t)K, bb + ldstB + 512);
  };
  auto wait_counted = [&]() {   // leave newest tile's loads (LPT_) outstanding
    if constexpr (BM == 128) asm volatile("s_waitcnt vmcnt(4)" ::: "memory");
    else                     asm volatile("s_waitcnt vmcnt(3)" ::: "memory");
  };

  f32x4 acc[MI][4];
#pragma unroll
  for (int i = 0; i < MI; ++i)
#pragma unroll
    for (int jj = 0; jj < 4; ++jj) acc[i][jj] = (f32x4){0.f, 0.f, 0.f, 0.f};

  const int ni = K >> 5;
  stage(0, a0, b0);
  stage(32, a1, b1);
  wait_counted();                                    // tile 0 landed
  __builtin_amdgcn_s_barrier();
  __builtin_amdgcn_sched_barrier(0);

  for (int it = 0; it < ni; ++it) {
    const bool pf = (it + 2) < ni;
    if (pf) stage((it + 2) << 5, a2, b2);
    short8 af[MI], bf[4];
#pragma unroll
    for (int i = 0; i < MI; ++i)
      af[i] = *reinterpret_cast<const short8*>(&a0[(wr + 16 * i + lr) * 32 + ko]);
#pragma unroll
    for (int jj = 0; jj < 4; ++jj)
      bf[jj] = *reinterpret_cast<const short8*>(&b0[(wc + 16 * jj + lr) * 32 + ko]);
    __builtin_amdgcn_s_setprio(1);
#pragma unroll
    for (int i = 0; i < MI; ++i)
#pragma unroll
      for (int jj = 0; jj < 4; ++jj)
        acc[i][jj] = __builtin_amdgcn_mfma_f32_16x16x32_bf16(af[i], bf[jj], acc[i][jj], 0, 0, 0);
    __builtin_amdgcn_s_setprio(0);
    if (it + 1 < ni) {
      if (pf) wait_counted();                        // tile it+1 landed
      else    asm volatile("s_waitcnt vmcnt(0)" ::: "memory");
      __builtin_amdgcn_s_barrier();
      __builtin_amdgcn_sched_barrier(0);
    }
    u16* tmp;
    tmp = a0; a0 = a1; a1 = a2; a2 = tmp;
    tmp = b0; b0 = b1; b1 = b2; b2 = tmp;
  }

  // C layout (16x16x32): col=lane&15, row=(lane>>4)*4+r  [m89/m91]
#pragma unroll
  for (int i = 0; i < MI; ++i) {
#pragma unroll
    for (int jj = 0; jj < 4; ++jj) {
      int col = n0 + wc + 16 * jj + lr;
      float bv = bias[col];
#pragma unroll
      for (int r = 0; r < 4; ++r) {
        int row = m0 + wr + 16 * i + lg * 4 + r;
        float val = (acc[i][jj][r] + bv) * cs;
        if (Cb) Cb[(size_t)row * ldc + ccol0 + col] = f2bf(val);
        else    Cf[(size_t)row * ldc + col] = val;
      }
    }
  }
}

// Q output pre-scaled by log2(e)/8 so attention softmax runs in exp2 domain.
#define QSCALE 0.18033688011112042f

__global__ __launch_bounds__(256) void gemm_qkv(const u16* __restrict__ Xq, const u16* __restrict__ Xk,
                                                const u16* __restrict__ Xv, const u16* __restrict__ Wq,
                                                const u16* __restrict__ Wk, const u16* __restrict__ Wv,
                                                const float* __restrict__ bq, const float* __restrict__ bk,
                                                const float* __restrict__ bv, u16* __restrict__ QKV) {
  const int z = blockIdx.z;
  const u16* A = z == 0 ? Xq : (z == 1 ? Xk : Xv);
  const u16* B = z == 0 ? Wq : (z == 1 ? Wk : Wv);
  const float* bias = z == 0 ? bq : (z == 1 ? bk : bv);
  gemm_core<128>(A, B, bias, QKV, nullptr, 1024, 3072, z * 1024, z == 0 ? QSCALE : 1.0f);
}

__global__ __launch_bounds__(256) void gemm_out(const u16* __restrict__ AO, const u16* __restrict__ Wo,
                                                const float* __restrict__ bo, float* __restrict__ out) {
  gemm_core<64>(AO, Wo, bo, nullptr, out, 1024, 1024, 0, 1.0f);
}

// ---------------- Flash attention (causal), dbuf KV, joint-64 softmax ----------------
// 4 waves x 32 q-rows = 128/block, grid (64,16) LPT. KV tile 64, double-buffered LDS
// -> ONE barrier per tile. flash2 fuses both 32-kv subtiles under a single
// max/rescale/defer (halves serial softmax; PV(s0) MFMA overlaps pack(s1) VALU).
// S^T = mfma(A=K, B=Q): lane owns q-col (l&31); kv row = (r&3)+8*(r>>2)+4*(l>>5).
// PV: O^T = mfma(A=V^T, B=P). Q pre-scaled by log2(e)/8 -> exp2-domain softmax.
#define LDK 72
#define DEFER_THR 11.0f

__global__ __launch_bounds__(256, 3) void attn_fwd(const u16* __restrict__ QKV, u16* __restrict__ O) {
  __shared__ __align__(16) u16 Kt[2][64 * LDK];
  __shared__ __align__(16) u16 Vt[2][64 * LDK];   // transposed [d][kv]

  const int t = threadIdx.x, l = t & 63, w = t >> 6;
  const int lq = l & 31, hi = l >> 5;
  const int bh = blockIdx.x;                   // 0..63
  const int qb = 15 - (int)blockIdx.y;         // 15..0, longest blocks first
  const int b = bh >> 4, h = bh & 15;
  const size_t rowb = (size_t)b * 2048;
  const int qcol = h * 64, kcol = 1024 + h * 64, vcol = 2048 + h * 64;
  const int q0w = qb * 128 + 32 * w;           // this wave's 32 q rows
  const int nt = 2 * qb + 2;                   // KV tiles of 64

  short8 qf[4];
  {
    const u16* qp = QKV + (rowb + q0w + lq) * 3072 + qcol + hi * 8;
#pragma unroll
    for (int ks = 0; ks < 4; ++ks) qf[ks] = *reinterpret_cast<const short8*>(qp + ks * 16);
  }

  f32x16 oa[2];
#pragma unroll
  for (int dt = 0; dt < 2; ++dt)
#pragma unroll
    for (int r = 0; r < 16; ++r) oa[dt][r] = 0.f;
  float m_run = -1e30f, l_run = 0.f;

  // staging maps (round-2 verbatim, measured 0 conflicts):
  // K: rows kr,kr+32 cols kc..kc+7; V: row-pairs 2kr,2kr+1 cols kc..kc+7
  const int kr = t & 31, kc = (t >> 5) * 8;    // t>>5 in 0..7
  short8 ka0, ka1;
  u16x8 va0, va1;

  auto stage_load = [&](int kv64) {
    const u16* kp = QKV + (rowb + (size_t)kv64 * 64 + kr) * 3072 + kcol + kc;
    ka0 = *reinterpret_cast<const short8*>(kp);
    ka1 = *reinterpret_cast<const short8*>(kp + 32 * 3072);
    const u16* vp = QKV + (rowb + (size_t)kv64 * 64 + 2 * kr) * 3072 + vcol + kc;
    va0 = *reinterpret_cast<const u16x8*>(vp);
    va1 = *reinterpret_cast<const u16x8*>(vp + 3072);
  };
  auto stage_write = [&](int buf) {
    *reinterpret_cast<short8*>(&Kt[buf][kr * LDK + kc]) = ka0;
    *reinterpret_cast<short8*>(&Kt[buf][(kr + 32) * LDK + kc]) = ka1;
#pragma unroll
    for (int jj = 0; jj < 8; ++jj) {
      u32 pk = (u32)va0[jj] | ((u32)va1[jj] << 16);
      *reinterpret_cast<u32*>(&Vt[buf][(kc + jj) * LDK + 2 * kr]) = pk;
    }
  };

  auto packP = [&](const f32x16& p, short8 pf[2]) {
    u32 P[8], X[8];
#pragma unroll
    for (int m2 = 0; m2 < 8; ++m2) {
      P[m2] = cvtpk(p[2 * m2], p[2 * m2 + 1]);
      X[m2] = (u32)__shfl_xor((int)P[m2], 32);
    }
#pragma unroll
    for (int ks2 = 0; ks2 < 2; ++ks2) {
      union { u32 u[4]; short8 v; } uu;
      uu.u[0] = hi ? X[4 * ks2 + 2] : P[4 * ks2 + 0];
      uu.u[1] = hi ? X[4 * ks2 + 3] : P[4 * ks2 + 1];
      uu.u[2] = hi ? P[4 * ks2 + 2] : X[4 * ks2 + 0];
      uu.u[3] = hi ? P[4 * ks2 + 3] : X[4 * ks2 + 1];
      pf[ks2] = uu.v;
    }
  };
  auto pvStep = [&](const u16* Vtc, int kt32, const short8 pf[2]) {
    __builtin_amdgcn_s_setprio(1);
#pragma unroll
    for (int ks2 = 0; ks2 < 2; ++ks2)
#pragma unroll
      for (int dt = 0; dt < 2; ++dt) {
        short8 vf = *reinterpret_cast<const short8*>(
            &Vtc[(dt * 32 + lq) * LDK + kt32 + ks2 * 16 + hi * 8]);
        oa[dt] = __builtin_amdgcn_mfma_f32_32x32x16_bf16(vf, pf[ks2], oa[dt], 0, 0, 0);
      }
    __builtin_amdgcn_s_setprio(0);
  };
  auto rescale_sum = [&](float pm) {
    if (!__all(pm <= m_run + DEFER_THR)) {         // T13 threshold defer
      float mnew = fmaxf(m_run, pm);
      float al = ex2(m_run - mnew);
      l_run *= al;
#pragma unroll
      for (int dt = 0; dt < 2; ++dt)
#pragma unroll
        for (int r = 0; r < 16; ++r) oa[dt][r] *= al;
      m_run = mnew;
    }
  };

  // both 32-kv subtiles valid; diag possibly on subtile 1
  auto flash2 = [&](const u16* Ktc, const u16* Vtc, bool diag1) {
    f32x16 s0, s1;
#pragma unroll
    for (int r = 0; r < 16; ++r) { s0[r] = 0.f; s1[r] = 0.f; }
    __builtin_amdgcn_s_setprio(1);
#pragma unroll
    for (int ks = 0; ks < 4; ++ks) {
      short8 kf = *reinterpret_cast<const short8*>(&Ktc[lq * LDK + ks * 16 + hi * 8]);
      s0 = __builtin_amdgcn_mfma_f32_32x32x16_bf16(kf, qf[ks], s0, 0, 0, 0);
    }
#pragma unroll
    for (int ks = 0; ks < 4; ++ks) {
      short8 kf = *reinterpret_cast<const short8*>(&Ktc[(32 + lq) * LDK + ks * 16 + hi * 8]);
      s1 = __builtin_amdgcn_mfma_f32_32x32x16_bf16(kf, qf[ks], s1, 0, 0, 0);
    }
    __builtin_amdgcn_s_setprio(0);
    if (diag1) {
#pragma unroll
      for (int r = 0; r < 16; ++r) {
        int off = (r & 3) + 8 * (r >> 2) + 4 * hi;
        if (off > lq) s1[r] = -1e30f;
      }
    }
    float pm = fmaxf(s0[0], s1[0]);
#pragma unroll
    for (int r = 1; r < 16; ++r) pm = fmaxf(pm, fmaxf(s0[r], s1[r]));
    pm = fmaxf(pm, __shfl_xor(pm, 32));
    rescale_sum(pm);
    float ps = 0.f;
#pragma unroll
    for (int r = 0; r < 16; ++r) { float e = ex2(s0[r] - m_run); s0[r] = e; ps += e; }
#pragma unroll
    for (int r = 0; r < 16; ++r) { float e = ex2(s1[r] - m_run); s1[r] = e; ps += e; }
    ps += __shfl_xor(ps, 32);
    l_run += ps;
    short8 pf[2];
    packP(s0, pf);
    pvStep(Vtc, 0, pf);        // PV(s0) MFMA overlaps pack(s1) VALU
    packP(s1, pf);
    pvStep(Vtc, 32, pf);
  };

  // only subtile 0 valid, on the diagonal
  auto flash1 = [&](const u16* Ktc, const u16* Vtc) {
    f32x16 s;
#pragma unroll
    for (int r = 0; r < 16; ++r) s[r] = 0.f;
    __builtin_amdgcn_s_setprio(1);
#pragma unroll
    for (int ks = 0; ks < 4; ++ks) {
      short8 kf = *reinterpret_cast<const short8*>(&Ktc[lq * LDK + ks * 16 + hi * 8]);
      s = __builtin_amdgcn_mfma_f32_32x32x16_bf16(kf, qf[ks], s, 0, 0, 0);
    }
    __builtin_amdgcn_s_setprio(0);
#pragma unroll
    for (int r = 0; r < 16; ++r) {
      int off = (r & 3) + 8 * (r >> 2) + 4 * hi;
      if (off > lq) s[r] = -1e30f;
    }
    float pm = s[0];
#pragma unroll
    for (int r = 1; r < 16; ++r) pm = fmaxf(pm, s[r]);
    pm = fmaxf(pm, __shfl_xor(pm, 32));
    rescale_sum(pm);
    float ps = 0.f;
#pragma unroll
    for (int r = 0; r < 16; ++r) { float e = ex2(s[r] - m_run); s[r] = e; ps += e; }
    ps += __shfl_xor(ps, 32);
    l_run += ps;
    short8 pf[2];
    packP(s, pf);
    pvStep(Vtc, 0, pf);
  };

  // prologue
  stage_load(0);
  stage_write(0);
  __syncthreads();

  for (int kb = 0; kb < nt; ++kb) {
    const int cur = kb & 1;
    const u16* Ktc = &Kt[cur][0];
    const u16* Vtc = &Vt[cur][0];
    if (kb + 1 < nt) stage_load(kb + 1);        // T14: issue loads before compute
    const int rel = q0w - kb * 64;
    if (rel >= 32)      flash2(Ktc, Vtc, rel == 32);
    else if (rel == 0)  flash1(Ktc, Vtc);
    if (kb + 1 < nt) stage_write(cur ^ 1);      // write OTHER buffer: no read race
    __syncthreads();                            // single barrier per tile
  }

  // epilogue: normalize, lane-half exchange to d-contiguous chunks, 16B stores
  const float inv = __builtin_amdgcn_rcpf(l_run);
  const size_t obase = (rowb + q0w + lq) * 1024 + h * 64;
#pragma unroll
  for (int dt = 0; dt < 2; ++dt) {
    u32 Bp[8], Xb[8];
#pragma unroll
    for (int m2 = 0; m2 < 8; ++m2) {
      Bp[m2] = cvtpk(oa[dt][2 * m2] * inv, oa[dt][2 * m2 + 1] * inv);
      Xb[m2] = (u32)__shfl_xor((int)Bp[m2], 32);
    }
    if (hi == dt) {
#pragma unroll
      for (int c = 0; c < 4; ++c) {
        union { u32 u[4]; short8 v; } uu;
        uu.u[0] = hi ? Xb[2 * c]     : Bp[2 * c];
        uu.u[1] = hi ? Xb[2 * c + 1] : Bp[2 * c + 1];
        uu.u[2] = hi ? Bp[2 * c]     : Xb[2 * c];
        uu.u[3] = hi ? Bp[2 * c + 1] : Xb[2 * c + 1];
        *reinterpret_cast<short8*>(&O[obase + dt * 32 + c * 8]) = uu.v;
      }
    }
  }
}

// ---------------- host launch ----------------
extern "C" void kernel_launch(void* const* d_in, const int* in_sizes, int n_in,
                              void* d_out, int out_size, void* d_ws, size_t ws_size,
                              hipStream_t stream) {
  const float* q  = (const float*)d_in[0];
  const float* k  = (const float*)d_in[1];
  const float* v  = (const float*)d_in[2];
  // d_in[3] = mask: known causal tril -> applied analytically
  const float* wq = (const float*)d_in[4];
  const float* bq = (const float*)d_in[5];
  const float* wk = (const float*)d_in[6];
  const float* bk = (const float*)d_in[7];
  const float* wv = (const float*)d_in[8];
  const float* bv = (const float*)d_in[9];
  const float* wo = (const float*)d_in[10];
  const float* bo = (const float*)d_in[11];
  float* out = (float*)d_out;

  u16* ws = (u16*)d_ws;
  const size_t NE = 8192ull * 1024;
  const size_t WE = 1024ull * 1024;
  u16* Xq   = ws;
  u16* Xk   = Xq + NE;
  u16* Xv   = Xk + NE;
  u16* Wq   = Xv + NE;
  u16* Wk   = Wq + WE;
  u16* Wv   = Wk + WE;
  u16* Wo   = Wv + WE;
  u16* QKVp = Wo + WE;                  // [8192][3072]
  u16* AO   = QKVp + 8192ull * 3072;    // [8192][1024]

  cvt_all<<<3 * NB + 4 * WB, 256, 0, stream>>>(q, k, v, wq, wk, wv, wo,
                                               Xq, Xk, Xv, Wq, Wk, Wv, Wo);

  gemm_qkv<<<dim3(8, 64, 3), 256, 0, stream>>>(Xq, Xk, Xv, Wq, Wk, Wv, bq, bk, bv, QKVp);

  attn_fwd<<<dim3(64, 16), 256, 0, stream>>>(QKVp, AO);

  gemm_out<<<dim3(8, 128), 256, 0, stream>>>(AO, Wo, bo, out);
}